// Round 4
// baseline (21005.217 us; speedup 1.0000x reference)
//
#include <hip/hip_runtime.h>
#include <hip/hip_bf16.h>

typedef __attribute__((ext_vector_type(4))) float f32x4;
typedef __attribute__((ext_vector_type(8))) __bf16 bf16x8;
typedef __attribute__((ext_vector_type(8))) unsigned short ushort8;

#define L_LAYERS 12
#define D_MODEL  1024
#define B_BATCH  16
#define T_TIME   2000
#define M_ROWS   (T_TIME * B_BATCH)   // 32000
#define H_HEADS  16
#define DH       64
#define SEGL     20
#define NSEG     (T_TIME / SEGL)      // 100

// ---------- helpers ----------
__device__ __forceinline__ void gload_lds16(const void* g, void* l) {
  __builtin_amdgcn_global_load_lds((const __attribute__((address_space(1))) void*)g,
                                   (__attribute__((address_space(3))) void*)l, 16, 0, 0);
}
__device__ __forceinline__ float bf2f(unsigned short u) {
  union { unsigned int i; float f; } x; x.i = ((unsigned)u) << 16; return x.f;
}
__device__ __forceinline__ unsigned short f2bf(float f) {
  union { __hip_bfloat16 h; unsigned short u; } x; x.h = __float2bfloat16(f); return x.u;
}

// ---------- x (B,T,D) -> h (T*B, D) fp32 ----------
__global__ __launch_bounds__(256)
void xpose(const float* __restrict__ x, float* __restrict__ h) {
  const int r = blockIdx.x;            // r = t*16 + b
  const int t = r >> 4, b = r & 15;
  reinterpret_cast<float4*>(h + (size_t)r * D_MODEL)[threadIdx.x] =
      reinterpret_cast<const float4*>(x + ((size_t)b * T_TIME + t) * D_MODEL)[threadIdx.x];
}

// ---------- weight transpose fp32 W[Kd][Nd] -> bf16 Wt[Nd][Kd], batched over z ----------
__global__ __launch_bounds__(256)
void trans_w(const float* __restrict__ W, __hip_bfloat16* __restrict__ Wt, int Kd, int Nd) {
  __shared__ float tbuf[32][33];
  const size_t base = (size_t)blockIdx.z * Kd * Nd;
  const int n0 = blockIdx.x * 32, k0 = blockIdx.y * 32;
  const int tx = threadIdx.x & 31, ty = threadIdx.x >> 5;
#pragma unroll
  for (int i = 0; i < 4; i++)
    tbuf[ty + i * 8][tx] = W[base + (size_t)(k0 + ty + i * 8) * Nd + n0 + tx];
  __syncthreads();
#pragma unroll
  for (int i = 0; i < 4; i++)
    Wt[base + (size_t)(n0 + ty + i * 8) * Kd + k0 + tx] = __float2bfloat16(tbuf[tx][ty + i * 8]);
}

// ---------- LayerNorm: fp32 in, bf16 or fp32 out (in-place safe: row read before write) ----------
template <int BF16OUT>
__global__ __launch_bounds__(256)
void ln_k(const float* __restrict__ in, void* __restrict__ out,
          const float* __restrict__ gamma, const float* __restrict__ beta) {
  const int r = blockIdx.x, t = threadIdx.x;
  const float4 v = reinterpret_cast<const float4*>(in + (size_t)r * D_MODEL)[t];
  float s  = v.x + v.y + v.z + v.w;
  float sq = v.x * v.x + v.y * v.y + v.z * v.z + v.w * v.w;
#pragma unroll
  for (int off = 32; off >= 1; off >>= 1) {
    s  += __shfl_xor(s, off);
    sq += __shfl_xor(sq, off);
  }
  __shared__ float ss[4], ssq[4];
  if ((t & 63) == 0) { ss[t >> 6] = s; ssq[t >> 6] = sq; }
  __syncthreads();
  s  = ss[0] + ss[1] + ss[2] + ss[3];
  sq = ssq[0] + ssq[1] + ssq[2] + ssq[3];
  const float mu   = s * (1.0f / D_MODEL);
  const float var  = sq * (1.0f / D_MODEL) - mu * mu;
  const float rstd = rsqrtf(var + 1e-5f);
  const float4 g = reinterpret_cast<const float4*>(gamma)[t];
  const float4 bb = reinterpret_cast<const float4*>(beta)[t];
  const float o0 = (v.x - mu) * rstd * g.x + bb.x;
  const float o1 = (v.y - mu) * rstd * g.y + bb.y;
  const float o2 = (v.z - mu) * rstd * g.z + bb.z;
  const float o3 = (v.w - mu) * rstd * g.w + bb.w;
  if constexpr (BF16OUT) {
    unsigned short pk[4] = {f2bf(o0), f2bf(o1), f2bf(o2), f2bf(o3)};
    *reinterpret_cast<uint2*>((__hip_bfloat16*)out + (size_t)r * D_MODEL + t * 4) =
        *reinterpret_cast<uint2*>(pk);
  } else {
    float4 o; o.x = o0; o.y = o1; o.z = o2; o.w = o3;
    reinterpret_cast<float4*>((float*)out)[(size_t)r * (D_MODEL / 4) + t] = o;
  }
}

// ---------- GEMM: C(MxN) = A(MxK bf16) * Bt(NxK bf16)^T, m97 structure ----------
// EPI_F32RES supports Cv == resid (each element read+written once by one thread).
enum { EPI_BF16 = 0, EPI_RELU = 1, EPI_F32RES = 2 };

template <int EPI>
__global__ __launch_bounds__(256)
void gemm_bt(const __hip_bfloat16* __restrict__ A, const __hip_bfloat16* __restrict__ Bt,
             const float* __restrict__ bias, const float* __restrict__ resid,
             void* __restrict__ Cv, int N, int K) {
  __shared__ __hip_bfloat16 As[128][32];
  __shared__ __hip_bfloat16 Bs[128][32];
  const int tid = threadIdx.x;
  const int wv = tid >> 6, ln = tid & 63;
  const int nt = blockIdx.x, mt = blockIdx.y;
  const __hip_bfloat16* ag = A  + ((size_t)mt * 128 + wv * 32 + (ln >> 2)) * K + (ln & 3) * 8;
  const __hip_bfloat16* bg = Bt + ((size_t)nt * 128 + wv * 32 + (ln >> 2)) * K + (ln & 3) * 8;
  __hip_bfloat16* asb0 = &As[wv * 32][0];
  __hip_bfloat16* asb1 = &As[wv * 32 + 16][0];
  __hip_bfloat16* bsb0 = &Bs[wv * 32][0];
  __hip_bfloat16* bsb1 = &Bs[wv * 32 + 16][0];
  const int wr = wv >> 1, wc = wv & 1;
  const int lr = ln & 15, lk = ln >> 4;
  f32x4 acc[4][4] = {};
  for (int k0 = 0; k0 < K; k0 += 32) {
    gload_lds16(ag + k0, asb0);
    gload_lds16(ag + (size_t)16 * K + k0, asb1);
    gload_lds16(bg + k0, bsb0);
    gload_lds16(bg + (size_t)16 * K + k0, bsb1);
    __syncthreads();
    bf16x8 af[4], bfr[4];
#pragma unroll
    for (int m = 0; m < 4; m++)
      af[m] = *reinterpret_cast<const bf16x8*>(&As[wr * 64 + m * 16 + lr][lk * 8]);
#pragma unroll
    for (int n = 0; n < 4; n++)
      bfr[n] = *reinterpret_cast<const bf16x8*>(&Bs[wc * 64 + n * 16 + lr][lk * 8]);
#pragma unroll
    for (int m = 0; m < 4; m++)
#pragma unroll
      for (int n = 0; n < 4; n++)
        acc[m][n] = __builtin_amdgcn_mfma_f32_16x16x32_bf16(af[m], bfr[n], acc[m][n], 0, 0, 0);
    __syncthreads();
  }
  // epilogue: C/D layout col=lane&15, row=(lane>>4)*4+j
#pragma unroll
  for (int n = 0; n < 4; n++) {
    const int col = nt * 128 + wc * 64 + n * 16 + lr;
    const float bv = bias[col];
#pragma unroll
    for (int m = 0; m < 4; m++) {
      const size_t rbase = (size_t)mt * 128 + wr * 64 + m * 16 + lk * 4;
#pragma unroll
      for (int j = 0; j < 4; j++) {
        const size_t idx = (rbase + j) * (size_t)N + col;
        float v = acc[m][n][j] + bv;
        if constexpr (EPI == EPI_RELU) v = fmaxf(v, 0.0f);
        if constexpr (EPI == EPI_F32RES) {
          ((float*)Cv)[idx] = v + resid[idx];
        } else {
          ((__hip_bfloat16*)Cv)[idx] = __float2bfloat16(v);
        }
      }
    }
  }
}

// ---------- block-diagonal attention (SEG=20, mask all-valid; ctx may alias q) ----------
// v3: 40KB LDS, K/V phase-split through the same buffer; global_load_lds staging;
// sched_barrier(0) fences cap scheduler load-hoisting (round-2/3 scratch-spill fix);
// all per-thread arrays statically indexed via full unroll.
__global__ __launch_bounds__(320)
void attn_k(const __hip_bfloat16* __restrict__ q, const __hip_bfloat16* __restrict__ kv,
            __hip_bfloat16* __restrict__ ctx) {
  __shared__ __hip_bfloat16 kvls[SEGL][D_MODEL];   // 40 KB, holds K then V
  const int sb = blockIdx.x;
  const int s = sb >> 4, b = sb & 15;
  const size_t row0 = (size_t)s * SEGL * B_BATCH + b;   // global row of (t=s*20, b)
  const int tid = threadIdx.x;
  const int wave = tid >> 6, lane = tid & 63;
  // ---- stage K: chunk c in [0,2560), 16B each; LDS dest linear in tid -> global_load_lds ok
#pragma unroll
  for (int it = 0; it < 8; it++) {
    const int c = it * 320 + tid;
    const int j = c >> 7, off = (c & 127) * 8;
    const size_t gr = (row0 + (size_t)j * B_BATCH) * (2 * D_MODEL);
    gload_lds16(kv + gr + off, (char*)kvls + (it * 320 + wave * 64) * 16);
  }
  const int hd = tid / SEGL, i = tid % SEGL;
  // q row, packed bf16: 8 x ushort8 = 32 VGPRs (each byte later overwritten only by this thread)
  ushort8 qv[8];
  const __hip_bfloat16* qp = q + (row0 + (size_t)i * B_BATCH) * D_MODEL + hd * DH;
#pragma unroll
  for (int c = 0; c < 8; c++) qv[c] = reinterpret_cast<const ushort8*>(qp)[c];
  __syncthreads();
  // ---- scores; sched_barrier per j keeps <=8 ds_read results live (no spill)
  float sc[SEGL];
#pragma unroll
  for (int j = 0; j < SEGL; j++) {
    float a0 = 0, a1 = 0;
#pragma unroll
    for (int c = 0; c < 8; c++) {
      ushort8 u = *reinterpret_cast<const ushort8*>(&kvls[j][hd * DH + c * 8]);
#pragma unroll
      for (int e = 0; e < 8; e += 2) {
        a0 += bf2f(qv[c][e]) * bf2f(u[e]);
        a1 += bf2f(qv[c][e + 1]) * bf2f(u[e + 1]);
      }
    }
    sc[j] = (a0 + a1) * 0.125f;   // 1/sqrt(64)
    __builtin_amdgcn_sched_barrier(0);
  }
  __syncthreads();               // all K reads done -> LDS reusable
  // ---- stage V into same LDS; softmax (register-only) overlaps the flight
#pragma unroll
  for (int it = 0; it < 8; it++) {
    const int c = it * 320 + tid;
    const int j = c >> 7, off = (c & 127) * 8;
    const size_t gr = (row0 + (size_t)j * B_BATCH) * (2 * D_MODEL) + D_MODEL;
    gload_lds16(kv + gr + off, (char*)kvls + (it * 320 + wave * 64) * 16);
  }
  float mx = sc[0];
#pragma unroll
  for (int j = 1; j < SEGL; j++) mx = fmaxf(mx, sc[j]);
  float sum = 0.0f;
#pragma unroll
  for (int j = 0; j < SEGL; j++) { sc[j] = __expf(sc[j] - mx); sum += sc[j]; }
  const float inv = 1.0f / sum;
#pragma unroll
  for (int j = 0; j < SEGL; j++) sc[j] *= inv;
  __syncthreads();
  // ---- PV: d-chunk-outer (8 fp32 acc live), 5-j sub-chunks fenced (<=5 ds_reads hoisted)
  __hip_bfloat16* op = ctx + (row0 + (size_t)i * B_BATCH) * D_MODEL + hd * DH;
#pragma unroll
  for (int d0 = 0; d0 < 64; d0 += 8) {
    float acc[8] = {};
#pragma unroll
    for (int j0 = 0; j0 < SEGL; j0 += 5) {
#pragma unroll
      for (int jj = 0; jj < 5; jj++) {
        ushort8 u = *reinterpret_cast<const ushort8*>(&kvls[j0 + jj][hd * DH + d0]);
#pragma unroll
        for (int e = 0; e < 8; e++) acc[e] += sc[j0 + jj] * bf2f(u[e]);
      }
      __builtin_amdgcn_sched_barrier(0);
    }
    unsigned short pk[8];
#pragma unroll
    for (int e = 0; e < 8; e++) pk[e] = f2bf(acc[e]);
    *reinterpret_cast<uint4*>(op + d0) = *reinterpret_cast<uint4*>(pk);
  }
}

// ---------- final: pooled = mean_b h ; out = pooled @ fc_w + fc_b ----------
__global__ __launch_bounds__(256)
void pool_fc(const float* __restrict__ h, const float* __restrict__ fcw,
             const float* __restrict__ fcb, float* __restrict__ out) {
  const int t = blockIdx.x, tid = threadIdx.x;
  float ax = 0, ay = 0, az = 0, aw = 0;
#pragma unroll
  for (int b = 0; b < B_BATCH; b++) {
    float4 v = reinterpret_cast<const float4*>(h + ((size_t)t * B_BATCH + b) * D_MODEL)[tid];
    ax += v.x; ay += v.y; az += v.z; aw += v.w;
  }
  const int d0 = tid * 4;
  float pacc[5];
#pragma unroll
  for (int c = 0; c < 5; c++)
    pacc[c] = (ax * fcw[(d0 + 0) * 5 + c] + ay * fcw[(d0 + 1) * 5 + c] +
               az * fcw[(d0 + 2) * 5 + c] + aw * fcw[(d0 + 3) * 5 + c]) * (1.0f / B_BATCH);
#pragma unroll
  for (int off = 32; off >= 1; off >>= 1)
#pragma unroll
    for (int c = 0; c < 5; c++) pacc[c] += __shfl_xor(pacc[c], off);
  __shared__ float red[4][5];
  if ((tid & 63) == 0) {
#pragma unroll
    for (int c = 0; c < 5; c++) red[tid >> 6][c] = pacc[c];
  }
  __syncthreads();
  if (tid < 5)
    out[(size_t)t * 5 + tid] = red[0][tid] + red[1][tid] + red[2][tid] + red[3][tid] + fcb[tid];
}

// ---------- launch ----------
extern "C" void kernel_launch(void* const* d_in, const int* in_sizes, int n_in,
                              void* d_out, int out_size, void* d_ws, size_t ws_size,
                              hipStream_t stream) {
  const float* x    = (const float*)d_in[0];
  const float* lnp  = (const float*)d_in[2];
  const float* Wq   = (const float*)d_in[3];
  const float* bq   = (const float*)d_in[4];
  const float* Wkv  = (const float*)d_in[5];
  const float* bkv  = (const float*)d_in[6];
  const float* Wout = (const float*)d_in[7];
  const float* bout = (const float*)d_in[8];
  const float* W1   = (const float*)d_in[9];
  const float* b1   = (const float*)d_in[10];
  const float* W2   = (const float*)d_in[11];
  const float* b2   = (const float*)d_in[12];
  const float* fcw  = (const float*)d_in[13];
  const float* fcb  = (const float*)d_in[14];

  char* p = (char*)d_ws;
  size_t off = 0;
  auto take = [&](size_t bytes) -> char* { char* q = p + off; off += (bytes + 255) & ~(size_t)255; return q; };

  // Minimal-footprint activation set (~393 MB):
  //  h   : fp32 residual stream, updated in place
  //  hn  : bf16 LN output
  //  qb  : bf16 q; attention ctx written in place over qb
  //  kvb : bf16 [k|v]; FFN intermediate f1 reuses this buffer
  float* h            = (float*)take((size_t)M_ROWS * D_MODEL * 4);
  __hip_bfloat16* hn  = (__hip_bfloat16*)take((size_t)M_ROWS * D_MODEL * 2);
  __hip_bfloat16* qb  = (__hip_bfloat16*)take((size_t)M_ROWS * D_MODEL * 2);
  __hip_bfloat16* kvb = (__hip_bfloat16*)take((size_t)M_ROWS * 2 * D_MODEL * 2);
  __hip_bfloat16* f1  = kvb;   // alias: kv dead once ctx computed

  const size_t WU = (size_t)L_LAYERS * D_MODEL * D_MODEL * 2;  // one DxD bf16 tensor, all layers
  const bool full = ws_size >= off + 6 * WU + (size_t)(16 << 20);

  __hip_bfloat16 *WqT, *WkvT, *WoutT, *W1T, *W2T;
  if (full) {
    WqT   = (__hip_bfloat16*)take(WU);
    WkvT  = (__hip_bfloat16*)take(2 * WU);
    WoutT = (__hip_bfloat16*)take(WU);
    W1T   = (__hip_bfloat16*)take(WU);
    W2T   = (__hip_bfloat16*)take(WU);
    trans_w<<<dim3(32, 32, L_LAYERS), 256, 0, stream>>>(Wq,   WqT,   D_MODEL, D_MODEL);
    trans_w<<<dim3(64, 32, L_LAYERS), 256, 0, stream>>>(Wkv,  WkvT,  D_MODEL, 2 * D_MODEL);
    trans_w<<<dim3(32, 32, L_LAYERS), 256, 0, stream>>>(Wout, WoutT, D_MODEL, D_MODEL);
    trans_w<<<dim3(32, 32, L_LAYERS), 256, 0, stream>>>(W1,   W1T,   D_MODEL, D_MODEL);
    trans_w<<<dim3(32, 32, L_LAYERS), 256, 0, stream>>>(W2,   W2T,   D_MODEL, D_MODEL);
  } else {
    // per-layer staging (12 MB total)
    WqT   = (__hip_bfloat16*)take((size_t)D_MODEL * D_MODEL * 2);
    WkvT  = (__hip_bfloat16*)take((size_t)D_MODEL * 2 * D_MODEL * 2);
    WoutT = (__hip_bfloat16*)take((size_t)D_MODEL * D_MODEL * 2);
    W1T   = (__hip_bfloat16*)take((size_t)D_MODEL * D_MODEL * 2);
    W2T   = (__hip_bfloat16*)take((size_t)D_MODEL * D_MODEL * 2);
  }

  xpose<<<M_ROWS, 256, 0, stream>>>(x, h);

  for (int l = 0; l < L_LAYERS; l++) {
    const size_t lw = (size_t)l * D_MODEL * D_MODEL;
    const __hip_bfloat16* wq   = full ? WqT   + lw     : WqT;
    const __hip_bfloat16* wkv  = full ? WkvT  + 2 * lw : WkvT;
    const __hip_bfloat16* wout = full ? WoutT + lw     : WoutT;
    const __hip_bfloat16* w1   = full ? W1T   + lw     : W1T;
    const __hip_bfloat16* w2   = full ? W2T   + lw     : W2T;
    if (!full) {
      trans_w<<<dim3(32, 32, 1), 256, 0, stream>>>(Wq + lw,      WqT,   D_MODEL, D_MODEL);
      trans_w<<<dim3(64, 32, 1), 256, 0, stream>>>(Wkv + 2 * lw, WkvT,  D_MODEL, 2 * D_MODEL);
      trans_w<<<dim3(32, 32, 1), 256, 0, stream>>>(Wout + lw,    WoutT, D_MODEL, D_MODEL);
      trans_w<<<dim3(32, 32, 1), 256, 0, stream>>>(W1 + lw,      W1T,   D_MODEL, D_MODEL);
      trans_w<<<dim3(32, 32, 1), 256, 0, stream>>>(W2 + lw,      W2T,   D_MODEL, D_MODEL);
    }
    const float* g0 = lnp + ((size_t)l * 6 + 0) * D_MODEL;
    const float* g1 = lnp + ((size_t)l * 6 + 1) * D_MODEL;
    const float* g2 = lnp + ((size_t)l * 6 + 2) * D_MODEL;
    const float* g3 = lnp + ((size_t)l * 6 + 3) * D_MODEL;
    const float* g4 = lnp + ((size_t)l * 6 + 4) * D_MODEL;
    const float* g5 = lnp + ((size_t)l * 6 + 5) * D_MODEL;

    ln_k<1><<<M_ROWS, 256, 0, stream>>>(h, hn, g0, g1);
    gemm_bt<EPI_BF16>  <<<dim3(8, 250),  256, 0, stream>>>(hn, wq,  bq  + l * D_MODEL,     nullptr, qb,  D_MODEL,     D_MODEL);
    gemm_bt<EPI_BF16>  <<<dim3(16, 250), 256, 0, stream>>>(hn, wkv, bkv + l * 2 * D_MODEL, nullptr, kvb, 2 * D_MODEL, D_MODEL);
    attn_k<<<NSEG * B_BATCH, 320, 0, stream>>>(qb, kvb, qb);               // ctx in place over q
    gemm_bt<EPI_F32RES><<<dim3(8, 250),  256, 0, stream>>>(qb, wout, bout + l * D_MODEL, h, h, D_MODEL, D_MODEL);  // h += attn_out
    ln_k<1><<<M_ROWS, 256, 0, stream>>>(h, hn, g2, g3);
    gemm_bt<EPI_RELU>  <<<dim3(8, 250),  256, 0, stream>>>(hn, w1, b1 + l * D_MODEL, nullptr, f1, D_MODEL, D_MODEL);
    gemm_bt<EPI_F32RES><<<dim3(8, 250),  256, 0, stream>>>(f1, w2, b2 + l * D_MODEL, h, h, D_MODEL, D_MODEL);      // h += ffn
    ln_k<0><<<M_ROWS, 256, 0, stream>>>(h, h, g4, g5);                     // in-place post LN
  }

  pool_fc<<<T_TIME, 256, 0, stream>>>(h, fcw, fcb, (float*)d_out);
}

// Round 6
// 13473.883 us; speedup vs baseline: 1.5590x; 1.5590x over previous
//
#include <hip/hip_runtime.h>
#include <hip/hip_bf16.h>

typedef __attribute__((ext_vector_type(4))) float f32x4;
typedef __attribute__((ext_vector_type(8))) __bf16 bf16x8;
typedef __attribute__((ext_vector_type(8))) unsigned short ushort8;

#define L_LAYERS 12
#define D_MODEL  1024
#define B_BATCH  16
#define T_TIME   2000
#define M_ROWS   (T_TIME * B_BATCH)   // 32000
#define H_HEADS  16
#define DH       64
#define SEGL     20
#define NSEG     (T_TIME / SEGL)      // 100

// ---------- helpers ----------
__device__ __forceinline__ void gload_lds16(const void* g, void* l) {
  __builtin_amdgcn_global_load_lds((const __attribute__((address_space(1))) void*)g,
                                   (__attribute__((address_space(3))) void*)l, 16, 0, 0);
}
__device__ __forceinline__ float bf2f(unsigned short u) {
  union { unsigned int i; float f; } x; x.i = ((unsigned)u) << 16; return x.f;
}
__device__ __forceinline__ unsigned short f2bf(float f) {
  union { __hip_bfloat16 h; unsigned short u; } x; x.h = __float2bfloat16(f); return x.u;
}

// ---------- x (B,T,D) -> h (T*B, D) fp32 ----------
__global__ __launch_bounds__(256)
void xpose(const float* __restrict__ x, float* __restrict__ h) {
  const int r = blockIdx.x;            // r = t*16 + b
  const int t = r >> 4, b = r & 15;
  reinterpret_cast<float4*>(h + (size_t)r * D_MODEL)[threadIdx.x] =
      reinterpret_cast<const float4*>(x + ((size_t)b * T_TIME + t) * D_MODEL)[threadIdx.x];
}

// ---------- weight transpose fp32 W[Kd][Nd] -> bf16 Wt[Nd][Kd], batched over z ----------
__global__ __launch_bounds__(256)
void trans_w(const float* __restrict__ W, __hip_bfloat16* __restrict__ Wt, int Kd, int Nd) {
  __shared__ float tbuf[32][33];
  const size_t base = (size_t)blockIdx.z * Kd * Nd;
  const int n0 = blockIdx.x * 32, k0 = blockIdx.y * 32;
  const int tx = threadIdx.x & 31, ty = threadIdx.x >> 5;
#pragma unroll
  for (int i = 0; i < 4; i++)
    tbuf[ty + i * 8][tx] = W[base + (size_t)(k0 + ty + i * 8) * Nd + n0 + tx];
  __syncthreads();
#pragma unroll
  for (int i = 0; i < 4; i++)
    Wt[base + (size_t)(n0 + ty + i * 8) * Kd + k0 + tx] = __float2bfloat16(tbuf[tx][ty + i * 8]);
}

// ---------- LayerNorm: fp32 in, bf16 or fp32 out (in-place safe: row read before write) ----------
template <int BF16OUT>
__global__ __launch_bounds__(256)
void ln_k(const float* __restrict__ in, void* __restrict__ out,
          const float* __restrict__ gamma, const float* __restrict__ beta) {
  const int r = blockIdx.x, t = threadIdx.x;
  const float4 v = reinterpret_cast<const float4*>(in + (size_t)r * D_MODEL)[t];
  float s  = v.x + v.y + v.z + v.w;
  float sq = v.x * v.x + v.y * v.y + v.z * v.z + v.w * v.w;
#pragma unroll
  for (int off = 32; off >= 1; off >>= 1) {
    s  += __shfl_xor(s, off);
    sq += __shfl_xor(sq, off);
  }
  __shared__ float ss[4], ssq[4];
  if ((t & 63) == 0) { ss[t >> 6] = s; ssq[t >> 6] = sq; }
  __syncthreads();
  s  = ss[0] + ss[1] + ss[2] + ss[3];
  sq = ssq[0] + ssq[1] + ssq[2] + ssq[3];
  const float mu   = s * (1.0f / D_MODEL);
  const float var  = sq * (1.0f / D_MODEL) - mu * mu;
  const float rstd = rsqrtf(var + 1e-5f);
  const float4 g = reinterpret_cast<const float4*>(gamma)[t];
  const float4 bb = reinterpret_cast<const float4*>(beta)[t];
  const float o0 = (v.x - mu) * rstd * g.x + bb.x;
  const float o1 = (v.y - mu) * rstd * g.y + bb.y;
  const float o2 = (v.z - mu) * rstd * g.z + bb.z;
  const float o3 = (v.w - mu) * rstd * g.w + bb.w;
  if constexpr (BF16OUT) {
    unsigned short pk[4] = {f2bf(o0), f2bf(o1), f2bf(o2), f2bf(o3)};
    *reinterpret_cast<uint2*>((__hip_bfloat16*)out + (size_t)r * D_MODEL + t * 4) =
        *reinterpret_cast<uint2*>(pk);
  } else {
    float4 o; o.x = o0; o.y = o1; o.z = o2; o.w = o3;
    reinterpret_cast<float4*>((float*)out)[(size_t)r * (D_MODEL / 4) + t] = o;
  }
}

// ---------- GEMM: C(MxN) = A(MxK bf16) * Bt(NxK bf16)^T, m97 structure ----------
// EPI_F32RES supports Cv == resid (each element read+written once by one thread).
enum { EPI_BF16 = 0, EPI_RELU = 1, EPI_F32RES = 2 };

template <int EPI>
__global__ __launch_bounds__(256)
void gemm_bt(const __hip_bfloat16* __restrict__ A, const __hip_bfloat16* __restrict__ Bt,
             const float* __restrict__ bias, const float* __restrict__ resid,
             void* __restrict__ Cv, int N, int K) {
  __shared__ __hip_bfloat16 As[128][32];
  __shared__ __hip_bfloat16 Bs[128][32];
  const int tid = threadIdx.x;
  const int wv = tid >> 6, ln = tid & 63;
  const int nt = blockIdx.x, mt = blockIdx.y;
  const __hip_bfloat16* ag = A  + ((size_t)mt * 128 + wv * 32 + (ln >> 2)) * K + (ln & 3) * 8;
  const __hip_bfloat16* bg = Bt + ((size_t)nt * 128 + wv * 32 + (ln >> 2)) * K + (ln & 3) * 8;
  __hip_bfloat16* asb0 = &As[wv * 32][0];
  __hip_bfloat16* asb1 = &As[wv * 32 + 16][0];
  __hip_bfloat16* bsb0 = &Bs[wv * 32][0];
  __hip_bfloat16* bsb1 = &Bs[wv * 32 + 16][0];
  const int wr = wv >> 1, wc = wv & 1;
  const int lr = ln & 15, lk = ln >> 4;
  f32x4 acc[4][4] = {};
  for (int k0 = 0; k0 < K; k0 += 32) {
    gload_lds16(ag + k0, asb0);
    gload_lds16(ag + (size_t)16 * K + k0, asb1);
    gload_lds16(bg + k0, bsb0);
    gload_lds16(bg + (size_t)16 * K + k0, bsb1);
    __syncthreads();
    bf16x8 af[4], bfr[4];
#pragma unroll
    for (int m = 0; m < 4; m++)
      af[m] = *reinterpret_cast<const bf16x8*>(&As[wr * 64 + m * 16 + lr][lk * 8]);
#pragma unroll
    for (int n = 0; n < 4; n++)
      bfr[n] = *reinterpret_cast<const bf16x8*>(&Bs[wc * 64 + n * 16 + lr][lk * 8]);
#pragma unroll
    for (int m = 0; m < 4; m++)
#pragma unroll
      for (int n = 0; n < 4; n++)
        acc[m][n] = __builtin_amdgcn_mfma_f32_16x16x32_bf16(af[m], bfr[n], acc[m][n], 0, 0, 0);
    __syncthreads();
  }
  // epilogue: C/D layout col=lane&15, row=(lane>>4)*4+j
#pragma unroll
  for (int n = 0; n < 4; n++) {
    const int col = nt * 128 + wc * 64 + n * 16 + lr;
    const float bv = bias[col];
#pragma unroll
    for (int m = 0; m < 4; m++) {
      const size_t rbase = (size_t)mt * 128 + wr * 64 + m * 16 + lk * 4;
#pragma unroll
      for (int j = 0; j < 4; j++) {
        const size_t idx = (rbase + j) * (size_t)N + col;
        float v = acc[m][n][j] + bv;
        if constexpr (EPI == EPI_RELU) v = fmaxf(v, 0.0f);
        if constexpr (EPI == EPI_F32RES) {
          ((float*)Cv)[idx] = v + resid[idx];
        } else {
          ((__hip_bfloat16*)Cv)[idx] = __float2bfloat16(v);
        }
      }
    }
  }
}

// ---------- block-diagonal attention v5 ----------
// Same structure as v4 (scores in LDS, coalesced write-out) but ALL barriers are
// wave-uniform (outside divergent code) -- the v4 bug was __syncthreads() inside
// `if (active)` with a partially-active wave (UB + barrier-count mismatch).
__global__ __launch_bounds__(256)
void attn_k(const __hip_bfloat16* __restrict__ q, const __hip_bfloat16* __restrict__ kv,
            __hip_bfloat16* __restrict__ ctx) {
  __shared__ __hip_bfloat16 kls[SEGL][512];   // 20 KB: K slice; reused as ctx tile
  __shared__ __hip_bfloat16 vls[SEGL][512];   // 20 KB: V slice
  __shared__ float sls[8][SEGL][SEGL];        // 12.8 KB: scores S[h'][i][j] (per-thread rows)
  const int blk = blockIdx.x;
  const int hg = blk & 1;                     // head-group 0/1 (8 heads each)
  const int sb = blk >> 1;
  const int s = sb >> 4, b = sb & 15;
  const size_t row0 = (size_t)s * SEGL * B_BATCH + b;
  const int tid = threadIdx.x;
  const int wave = tid >> 6;
  const int colbase = hg * 512;               // column slice [colbase, colbase+512)
  // ---- stage K,V slices: 1280 16-B chunks each (linear LDS dest = chunk*16)
#pragma unroll
  for (int it = 0; it < 5; it++) {
    const int c = it * 256 + tid;
    const int j = c >> 6, off = (c & 63) * 8;
    gload_lds16(kv + (row0 + (size_t)j * B_BATCH) * (2 * D_MODEL) + colbase + off,
                (char*)kls + (it * 256 + wave * 64) * 16);
  }
#pragma unroll
  for (int it = 0; it < 5; it++) {
    const int c = it * 256 + tid;
    const int j = c >> 6, off = (c & 63) * 8;
    gload_lds16(kv + (row0 + (size_t)j * B_BATCH) * (2 * D_MODEL) + D_MODEL + colbase + off,
                (char*)vls + (it * 256 + wave * 64) * 16);
  }
  const bool active = tid < 8 * SEGL;         // 160 compute threads: (h', i)
  const int hh = tid / SEGL;                  // 0..7
  const int i  = tid % SEGL;                  // 0..19
  // q row in packed bf16: 8 x ushort8 = 32 VGPRs
  ushort8 qv[8];
  if (active) {
    const __hip_bfloat16* qp = q + (row0 + (size_t)i * B_BATCH) * D_MODEL + (colbase + hh * DH);
#pragma unroll
    for (int c = 0; c < 8; c++) qv[c] = reinterpret_cast<const ushort8*>(qp)[c];
  }
  __syncthreads();                            // B0: staging visible (uniform)
  float inv = 0.0f;                           // carried across the barrier in a register
  if (active) {
    // ---- scores -> LDS (no VGPR score array -> spill impossible)
#pragma unroll
    for (int j = 0; j < SEGL; j++) {
      float a0 = 0, a1 = 0;
#pragma unroll
      for (int c = 0; c < 8; c++) {
        ushort8 u = *reinterpret_cast<const ushort8*>(&kls[j][hh * DH + c * 8]);
#pragma unroll
        for (int e = 0; e < 8; e += 2) {
          a0 += bf2f(qv[c][e]) * bf2f(u[e]);
          a1 += bf2f(qv[c][e + 1]) * bf2f(u[e + 1]);
        }
      }
      sls[hh][i][j] = (a0 + a1) * 0.125f;     // 1/sqrt(64)
    }
    // ---- softmax over own row (exp written back; 1/sum kept in register)
    float mx = -1e30f;
    for (int j = 0; j < SEGL; j++) mx = fmaxf(mx, sls[hh][i][j]);
    float sum = 0.0f;
    for (int j = 0; j < SEGL; j++) { float e = __expf(sls[hh][i][j] - mx); sls[hh][i][j] = e; sum += e; }
    inv = 1.0f / sum;
  }
  __syncthreads();                            // B1: all kls reads done -> tile reusable (uniform)
  if (active) {
    // ---- PV: 8 fp32 acc live; result into LDS tile (kls region)
#pragma unroll
    for (int d0 = 0; d0 < DH; d0 += 8) {
      float acc[8] = {};
#pragma unroll
      for (int j = 0; j < SEGL; j++) {
        const float pj = sls[hh][i][j];
        ushort8 u = *reinterpret_cast<const ushort8*>(&vls[j][hh * DH + d0]);
#pragma unroll
        for (int e = 0; e < 8; e++) acc[e] += pj * bf2f(u[e]);
      }
      unsigned short pk[8];
#pragma unroll
      for (int e = 0; e < 8; e++) pk[e] = f2bf(acc[e] * inv);
      *reinterpret_cast<uint4*>(&kls[i][hh * DH + d0]) = *reinterpret_cast<uint4*>(pk);
    }
  }
  __syncthreads();                            // B2: tile complete (uniform)
  // ---- cooperative coalesced write-out: contiguous 1-KB per wave
#pragma unroll
  for (int it = 0; it < 5; it++) {
    const int c = it * 256 + tid;
    const int j = c >> 6, off = (c & 63) * 8;
    *reinterpret_cast<uint4*>(ctx + (row0 + (size_t)j * B_BATCH) * D_MODEL + colbase + off) =
        *reinterpret_cast<const uint4*>(&kls[j][off]);
  }
}

// ---------- final: pooled = mean_b h ; out = pooled @ fc_w + fc_b ----------
__global__ __launch_bounds__(256)
void pool_fc(const float* __restrict__ h, const float* __restrict__ fcw,
             const float* __restrict__ fcb, float* __restrict__ out) {
  const int t = blockIdx.x, tid = threadIdx.x;
  float ax = 0, ay = 0, az = 0, aw = 0;
#pragma unroll
  for (int b = 0; b < B_BATCH; b++) {
    float4 v = reinterpret_cast<const float4*>(h + ((size_t)t * B_BATCH + b) * D_MODEL)[tid];
    ax += v.x; ay += v.y; az += v.z; aw += v.w;
  }
  const int d0 = tid * 4;
  float pacc[5];
#pragma unroll
  for (int c = 0; c < 5; c++)
    pacc[c] = (ax * fcw[(d0 + 0) * 5 + c] + ay * fcw[(d0 + 1) * 5 + c] +
               az * fcw[(d0 + 2) * 5 + c] + aw * fcw[(d0 + 3) * 5 + c]) * (1.0f / B_BATCH);
#pragma unroll
  for (int off = 32; off >= 1; off >>= 1)
#pragma unroll
    for (int c = 0; c < 5; c++) pacc[c] += __shfl_xor(pacc[c], off);
  __shared__ float red[4][5];
  if ((tid & 63) == 0) {
#pragma unroll
    for (int c = 0; c < 5; c++) red[tid >> 6][c] = pacc[c];
  }
  __syncthreads();
  if (tid < 5)
    out[(size_t)t * 5 + tid] = red[0][tid] + red[1][tid] + red[2][tid] + red[3][tid] + fcb[tid];
}

// ---------- launch ----------
extern "C" void kernel_launch(void* const* d_in, const int* in_sizes, int n_in,
                              void* d_out, int out_size, void* d_ws, size_t ws_size,
                              hipStream_t stream) {
  const float* x    = (const float*)d_in[0];
  const float* lnp  = (const float*)d_in[2];
  const float* Wq   = (const float*)d_in[3];
  const float* bq   = (const float*)d_in[4];
  const float* Wkv  = (const float*)d_in[5];
  const float* bkv  = (const float*)d_in[6];
  const float* Wout = (const float*)d_in[7];
  const float* bout = (const float*)d_in[8];
  const float* W1   = (const float*)d_in[9];
  const float* b1   = (const float*)d_in[10];
  const float* W2   = (const float*)d_in[11];
  const float* b2   = (const float*)d_in[12];
  const float* fcw  = (const float*)d_in[13];
  const float* fcb  = (const float*)d_in[14];

  char* p = (char*)d_ws;
  size_t off = 0;
  auto take = [&](size_t bytes) -> char* { char* q = p + off; off += (bytes + 255) & ~(size_t)255; return q; };

  // Minimal-footprint activation set (~393 MB):
  //  h   : fp32 residual stream, updated in place
  //  hn  : bf16 LN output
  //  qb  : bf16 q; attention ctx written in place over qb
  //  kvb : bf16 [k|v]; FFN intermediate f1 reuses this buffer
  float* h            = (float*)take((size_t)M_ROWS * D_MODEL * 4);
  __hip_bfloat16* hn  = (__hip_bfloat16*)take((size_t)M_ROWS * D_MODEL * 2);
  __hip_bfloat16* qb  = (__hip_bfloat16*)take((size_t)M_ROWS * D_MODEL * 2);
  __hip_bfloat16* kvb = (__hip_bfloat16*)take((size_t)M_ROWS * 2 * D_MODEL * 2);
  __hip_bfloat16* f1  = kvb;   // alias: kv dead once ctx computed

  const size_t WU = (size_t)L_LAYERS * D_MODEL * D_MODEL * 2;  // one DxD bf16 tensor, all layers
  const bool full = ws_size >= off + 6 * WU + (size_t)(16 << 20);

  __hip_bfloat16 *WqT, *WkvT, *WoutT, *W1T, *W2T;
  if (full) {
    WqT   = (__hip_bfloat16*)take(WU);
    WkvT  = (__hip_bfloat16*)take(2 * WU);
    WoutT = (__hip_bfloat16*)take(WU);
    W1T   = (__hip_bfloat16*)take(WU);
    W2T   = (__hip_bfloat16*)take(WU);
    trans_w<<<dim3(32, 32, L_LAYERS), 256, 0, stream>>>(Wq,   WqT,   D_MODEL, D_MODEL);
    trans_w<<<dim3(64, 32, L_LAYERS), 256, 0, stream>>>(Wkv,  WkvT,  D_MODEL, 2 * D_MODEL);
    trans_w<<<dim3(32, 32, L_LAYERS), 256, 0, stream>>>(Wout, WoutT, D_MODEL, D_MODEL);
    trans_w<<<dim3(32, 32, L_LAYERS), 256, 0, stream>>>(W1,   W1T,   D_MODEL, D_MODEL);
    trans_w<<<dim3(32, 32, L_LAYERS), 256, 0, stream>>>(W2,   W2T,   D_MODEL, D_MODEL);
  } else {
    // per-layer staging (12 MB total)
    WqT   = (__hip_bfloat16*)take((size_t)D_MODEL * D_MODEL * 2);
    WkvT  = (__hip_bfloat16*)take((size_t)D_MODEL * 2 * D_MODEL * 2);
    WoutT = (__hip_bfloat16*)take((size_t)D_MODEL * D_MODEL * 2);
    W1T   = (__hip_bfloat16*)take((size_t)D_MODEL * D_MODEL * 2);
    W2T   = (__hip_bfloat16*)take((size_t)D_MODEL * D_MODEL * 2);
  }

  xpose<<<M_ROWS, 256, 0, stream>>>(x, h);

  for (int l = 0; l < L_LAYERS; l++) {
    const size_t lw = (size_t)l * D_MODEL * D_MODEL;
    const __hip_bfloat16* wq   = full ? WqT   + lw     : WqT;
    const __hip_bfloat16* wkv  = full ? WkvT  + 2 * lw : WkvT;
    const __hip_bfloat16* wout = full ? WoutT + lw     : WoutT;
    const __hip_bfloat16* w1   = full ? W1T   + lw     : W1T;
    const __hip_bfloat16* w2   = full ? W2T   + lw     : W2T;
    if (!full) {
      trans_w<<<dim3(32, 32, 1), 256, 0, stream>>>(Wq + lw,      WqT,   D_MODEL, D_MODEL);
      trans_w<<<dim3(64, 32, 1), 256, 0, stream>>>(Wkv + 2 * lw, WkvT,  D_MODEL, 2 * D_MODEL);
      trans_w<<<dim3(32, 32, 1), 256, 0, stream>>>(Wout + lw,    WoutT, D_MODEL, D_MODEL);
      trans_w<<<dim3(32, 32, 1), 256, 0, stream>>>(W1 + lw,      W1T,   D_MODEL, D_MODEL);
      trans_w<<<dim3(32, 32, 1), 256, 0, stream>>>(W2 + lw,      W2T,   D_MODEL, D_MODEL);
    }
    const float* g0 = lnp + ((size_t)l * 6 + 0) * D_MODEL;
    const float* g1 = lnp + ((size_t)l * 6 + 1) * D_MODEL;
    const float* g2 = lnp + ((size_t)l * 6 + 2) * D_MODEL;
    const float* g3 = lnp + ((size_t)l * 6 + 3) * D_MODEL;
    const float* g4 = lnp + ((size_t)l * 6 + 4) * D_MODEL;
    const float* g5 = lnp + ((size_t)l * 6 + 5) * D_MODEL;

    ln_k<1><<<M_ROWS, 256, 0, stream>>>(h, hn, g0, g1);
    gemm_bt<EPI_BF16>  <<<dim3(8, 250),  256, 0, stream>>>(hn, wq,  bq  + l * D_MODEL,     nullptr, qb,  D_MODEL,     D_MODEL);
    gemm_bt<EPI_BF16>  <<<dim3(16, 250), 256, 0, stream>>>(hn, wkv, bkv + l * 2 * D_MODEL, nullptr, kvb, 2 * D_MODEL, D_MODEL);
    attn_k<<<NSEG * B_BATCH * 2, 256, 0, stream>>>(qb, kvb, qb);           // ctx in place over q
    gemm_bt<EPI_F32RES><<<dim3(8, 250),  256, 0, stream>>>(qb, wout, bout + l * D_MODEL, h, h, D_MODEL, D_MODEL);  // h += attn_out
    ln_k<1><<<M_ROWS, 256, 0, stream>>>(h, hn, g2, g3);
    gemm_bt<EPI_RELU>  <<<dim3(8, 250),  256, 0, stream>>>(hn, w1, b1 + l * D_MODEL, nullptr, f1, D_MODEL, D_MODEL);
    gemm_bt<EPI_F32RES><<<dim3(8, 250),  256, 0, stream>>>(f1, w2, b2 + l * D_MODEL, h, h, D_MODEL, D_MODEL);      // h += ffn
    ln_k<0><<<M_ROWS, 256, 0, stream>>>(h, h, g4, g5);                     // in-place post LN
  }

  pool_fc<<<T_TIME, 256, 0, stream>>>(h, fcw, fcb, (float*)d_out);
}

// Round 7
// 11571.756 us; speedup vs baseline: 1.8152x; 1.1644x over previous
//
#include <hip/hip_runtime.h>
#include <hip/hip_bf16.h>

typedef __attribute__((ext_vector_type(4))) float f32x4;
typedef __attribute__((ext_vector_type(8))) __bf16 bf16x8;
typedef __attribute__((ext_vector_type(8))) unsigned short ushort8;

#define L_LAYERS 12
#define D_MODEL  1024
#define B_BATCH  16
#define T_TIME   2000
#define M_ROWS   (T_TIME * B_BATCH)   // 32000
#define H_HEADS  16
#define DH       64
#define SEGL     20
#define NSEG     (T_TIME / SEGL)      // 100
#define HGN      4                    // heads per attention block

// ---------- helpers ----------
__device__ __forceinline__ void gload_lds16(const void* g, void* l) {
  __builtin_amdgcn_global_load_lds((const __attribute__((address_space(1))) void*)g,
                                   (__attribute__((address_space(3))) void*)l, 16, 0, 0);
}
__device__ __forceinline__ float bf2f(unsigned short u) {
  union { unsigned int i; float f; } x; x.i = ((unsigned)u) << 16; return x.f;
}
__device__ __forceinline__ unsigned short f2bf(float f) {
  union { __hip_bfloat16 h; unsigned short u; } x; x.h = __float2bfloat16(f); return x.u;
}

// ---------- x (B,T,D) -> h (T*B, D) fp32 ----------
__global__ __launch_bounds__(256)
void xpose(const float* __restrict__ x, float* __restrict__ h) {
  const int r = blockIdx.x;            // r = t*16 + b
  const int t = r >> 4, b = r & 15;
  reinterpret_cast<float4*>(h + (size_t)r * D_MODEL)[threadIdx.x] =
      reinterpret_cast<const float4*>(x + ((size_t)b * T_TIME + t) * D_MODEL)[threadIdx.x];
}

// ---------- weight transpose fp32 W[Kd][Nd] -> bf16 Wt[Nd][Kd], batched over z ----------
__global__ __launch_bounds__(256)
void trans_w(const float* __restrict__ W, __hip_bfloat16* __restrict__ Wt, int Kd, int Nd) {
  __shared__ float tbuf[32][33];
  const size_t base = (size_t)blockIdx.z * Kd * Nd;
  const int n0 = blockIdx.x * 32, k0 = blockIdx.y * 32;
  const int tx = threadIdx.x & 31, ty = threadIdx.x >> 5;
#pragma unroll
  for (int i = 0; i < 4; i++)
    tbuf[ty + i * 8][tx] = W[base + (size_t)(k0 + ty + i * 8) * Nd + n0 + tx];
  __syncthreads();
#pragma unroll
  for (int i = 0; i < 4; i++)
    Wt[base + (size_t)(n0 + ty + i * 8) * Kd + k0 + tx] = __float2bfloat16(tbuf[tx][ty + i * 8]);
}

// ---------- LayerNorm: fp32 in, bf16 or fp32 out (in-place safe: row read before write) ----------
template <int BF16OUT>
__global__ __launch_bounds__(256)
void ln_k(const float* __restrict__ in, void* __restrict__ out,
          const float* __restrict__ gamma, const float* __restrict__ beta) {
  const int r = blockIdx.x, t = threadIdx.x;
  const float4 v = reinterpret_cast<const float4*>(in + (size_t)r * D_MODEL)[t];
  float s  = v.x + v.y + v.z + v.w;
  float sq = v.x * v.x + v.y * v.y + v.z * v.z + v.w * v.w;
#pragma unroll
  for (int off = 32; off >= 1; off >>= 1) {
    s  += __shfl_xor(s, off);
    sq += __shfl_xor(sq, off);
  }
  __shared__ float ss[4], ssq[4];
  if ((t & 63) == 0) { ss[t >> 6] = s; ssq[t >> 6] = sq; }
  __syncthreads();
  s  = ss[0] + ss[1] + ss[2] + ss[3];
  sq = ssq[0] + ssq[1] + ssq[2] + ssq[3];
  const float mu   = s * (1.0f / D_MODEL);
  const float var  = sq * (1.0f / D_MODEL) - mu * mu;
  const float rstd = rsqrtf(var + 1e-5f);
  const float4 g = reinterpret_cast<const float4*>(gamma)[t];
  const float4 bb = reinterpret_cast<const float4*>(beta)[t];
  const float o0 = (v.x - mu) * rstd * g.x + bb.x;
  const float o1 = (v.y - mu) * rstd * g.y + bb.y;
  const float o2 = (v.z - mu) * rstd * g.z + bb.z;
  const float o3 = (v.w - mu) * rstd * g.w + bb.w;
  if constexpr (BF16OUT) {
    unsigned short pk[4] = {f2bf(o0), f2bf(o1), f2bf(o2), f2bf(o3)};
    *reinterpret_cast<uint2*>((__hip_bfloat16*)out + (size_t)r * D_MODEL + t * 4) =
        *reinterpret_cast<uint2*>(pk);
  } else {
    float4 o; o.x = o0; o.y = o1; o.z = o2; o.w = o3;
    reinterpret_cast<float4*>((float*)out)[(size_t)r * (D_MODEL / 4) + t] = o;
  }
}

// ---------- GEMM: C(MxN) = A(MxK bf16) * Bt(NxK bf16)^T, m97 structure ----------
// EPI_F32RES supports Cv == resid (each element read+written once by one thread).
enum { EPI_BF16 = 0, EPI_RELU = 1, EPI_F32RES = 2 };

template <int EPI>
__global__ __launch_bounds__(256)
void gemm_bt(const __hip_bfloat16* __restrict__ A, const __hip_bfloat16* __restrict__ Bt,
             const float* __restrict__ bias, const float* __restrict__ resid,
             void* __restrict__ Cv, int N, int K) {
  __shared__ __hip_bfloat16 As[128][32];
  __shared__ __hip_bfloat16 Bs[128][32];
  const int tid = threadIdx.x;
  const int wv = tid >> 6, ln = tid & 63;
  const int nt = blockIdx.x, mt = blockIdx.y;
  const __hip_bfloat16* ag = A  + ((size_t)mt * 128 + wv * 32 + (ln >> 2)) * K + (ln & 3) * 8;
  const __hip_bfloat16* bg = Bt + ((size_t)nt * 128 + wv * 32 + (ln >> 2)) * K + (ln & 3) * 8;
  __hip_bfloat16* asb0 = &As[wv * 32][0];
  __hip_bfloat16* asb1 = &As[wv * 32 + 16][0];
  __hip_bfloat16* bsb0 = &Bs[wv * 32][0];
  __hip_bfloat16* bsb1 = &Bs[wv * 32 + 16][0];
  const int wr = wv >> 1, wc = wv & 1;
  const int lr = ln & 15, lk = ln >> 4;
  f32x4 acc[4][4] = {};
  for (int k0 = 0; k0 < K; k0 += 32) {
    gload_lds16(ag + k0, asb0);
    gload_lds16(ag + (size_t)16 * K + k0, asb1);
    gload_lds16(bg + k0, bsb0);
    gload_lds16(bg + (size_t)16 * K + k0, bsb1);
    __syncthreads();
    bf16x8 af[4], bfr[4];
#pragma unroll
    for (int m = 0; m < 4; m++)
      af[m] = *reinterpret_cast<const bf16x8*>(&As[wr * 64 + m * 16 + lr][lk * 8]);
#pragma unroll
    for (int n = 0; n < 4; n++)
      bfr[n] = *reinterpret_cast<const bf16x8*>(&Bs[wc * 64 + n * 16 + lr][lk * 8]);
#pragma unroll
    for (int m = 0; m < 4; m++)
#pragma unroll
      for (int n = 0; n < 4; n++)
        acc[m][n] = __builtin_amdgcn_mfma_f32_16x16x32_bf16(af[m], bfr[n], acc[m][n], 0, 0, 0);
    __syncthreads();
  }
  // epilogue: C/D layout col=lane&15, row=(lane>>4)*4+j
#pragma unroll
  for (int n = 0; n < 4; n++) {
    const int col = nt * 128 + wc * 64 + n * 16 + lr;
    const float bv = bias[col];
#pragma unroll
    for (int m = 0; m < 4; m++) {
      const size_t rbase = (size_t)mt * 128 + wr * 64 + m * 16 + lk * 4;
#pragma unroll
      for (int j = 0; j < 4; j++) {
        const size_t idx = (rbase + j) * (size_t)N + col;
        float v = acc[m][n][j] + bv;
        if constexpr (EPI == EPI_RELU) v = fmaxf(v, 0.0f);
        if constexpr (EPI == EPI_F32RES) {
          ((float*)Cv)[idx] = v + resid[idx];
        } else {
          ((__hip_bfloat16*)Cv)[idx] = __float2bfloat16(v);
        }
      }
    }
  }
}

// ---------- block-diagonal attention v6 ----------
// Spill made structurally impossible: j-loops are runtime loops (#pragma unroll 1),
// all j-indexed state is LDS-resident, VGPR capped via __launch_bounds__(256,4).
// Block = (s, b, head-group of 4): LDS 26.9 KB -> 4-6 blocks/CU. PV tile store uses
// rotated columns (i*8 within the 64-elem head slice) to break bank conflicts;
// write-out applies the inverse rotation. All barriers wave-uniform.
__global__ __launch_bounds__(256, 4)
void attn_k(const __hip_bfloat16* __restrict__ q, const __hip_bfloat16* __restrict__ kv,
            __hip_bfloat16* __restrict__ ctx) {
  __shared__ __hip_bfloat16 kls[SEGL][HGN * DH];   // 10 KB: K slice; reused as ctx tile
  __shared__ __hip_bfloat16 vls[SEGL][HGN * DH];   // 10 KB: V slice
  __shared__ float sls[HGN][SEGL][SEGL];           // 6.4 KB: scores
  const int blk = blockIdx.x;
  const int hg = blk & 3;                          // head-group 0..3 (4 heads each)
  const int sb = blk >> 2;
  const int s = sb >> 4, b = sb & 15;
  const size_t row0 = (size_t)s * SEGL * B_BATCH + b;
  const int tid = threadIdx.x;
  const int colbase = hg * (HGN * DH);             // 256-elem column slice
  // ---- stage K,V: 640 16-B chunks each; rows of 32 chunks; guards are wave-uniform
#pragma unroll
  for (int it = 0; it < 3; it++) {
    const int c = it * 256 + tid;
    if (c < SEGL * 32) {
      const int j = c >> 5, off = (c & 31) * 8;
      gload_lds16(kv + (row0 + (size_t)j * B_BATCH) * (2 * D_MODEL) + colbase + off,
                  (char*)kls + c * 16);
    }
  }
#pragma unroll
  for (int it = 0; it < 3; it++) {
    const int c = it * 256 + tid;
    if (c < SEGL * 32) {
      const int j = c >> 5, off = (c & 31) * 8;
      gload_lds16(kv + (row0 + (size_t)j * B_BATCH) * (2 * D_MODEL) + D_MODEL + colbase + off,
                  (char*)vls + c * 16);
    }
  }
  const bool active = tid < HGN * SEGL;            // 80 compute threads: (hh, i)
  const int hh = tid / SEGL;                       // 0..3
  const int i  = tid % SEGL;                       // 0..19
  // q row in packed bf16: 8 x ushort8 = 32 VGPRs
  ushort8 qv[8];
  if (active) {
    const __hip_bfloat16* qp = q + (row0 + (size_t)i * B_BATCH) * D_MODEL + (colbase + hh * DH);
#pragma unroll
    for (int c = 0; c < 8; c++) qv[c] = reinterpret_cast<const ushort8*>(qp)[c];
  }
  __syncthreads();                                 // B0: staging visible (uniform)
  float inv = 0.0f;
  if (active) {
    // ---- scores -> LDS. Runtime j-loop: <=1 iteration of LDS reads in flight.
#pragma unroll 1
    for (int j = 0; j < SEGL; j++) {
      float a0 = 0, a1 = 0;
#pragma unroll
      for (int c = 0; c < 8; c++) {
        ushort8 u = *reinterpret_cast<const ushort8*>(&kls[j][hh * DH + c * 8]);
#pragma unroll
        for (int e = 0; e < 8; e += 2) {
          a0 += bf2f(qv[c][e]) * bf2f(u[e]);
          a1 += bf2f(qv[c][e + 1]) * bf2f(u[e + 1]);
        }
      }
      sls[hh][i][j] = (a0 + a1) * 0.125f;          // 1/sqrt(64)
    }
    // ---- softmax over own row (runtime loops; row is LDS-resident)
    float mx = -1e30f;
#pragma unroll 1
    for (int j = 0; j < SEGL; j++) mx = fmaxf(mx, sls[hh][i][j]);
    float sum = 0.0f;
#pragma unroll 1
    for (int j = 0; j < SEGL; j++) { float e = __expf(sls[hh][i][j] - mx); sls[hh][i][j] = e; sum += e; }
    inv = 1.0f / sum;
  }
  __syncthreads();                                 // B1: kls reads done -> tile reusable (uniform)
  if (active) {
    // ---- PV: 8 fp32 acc live; runtime j-loop; tile store with rotated columns
#pragma unroll
    for (int d0 = 0; d0 < DH; d0 += 8) {
      float acc[8] = {};
#pragma unroll 1
      for (int j = 0; j < SEGL; j++) {
        const float pj = sls[hh][i][j];
        ushort8 u = *reinterpret_cast<const ushort8*>(&vls[j][hh * DH + d0]);
#pragma unroll
        for (int e = 0; e < 8; e++) acc[e] += pj * bf2f(u[e]);
      }
      unsigned short pk[8];
#pragma unroll
      for (int e = 0; e < 8; e++) pk[e] = f2bf(acc[e] * inv);
      const int colr = hh * DH + ((d0 + i * 8) & (DH - 1));   // rotate by i*8 within head slice
      *reinterpret_cast<uint4*>(&kls[i][colr]) = *reinterpret_cast<uint4*>(pk);
    }
  }
  __syncthreads();                                 // B2: tile complete (uniform)
  // ---- coalesced write-out with inverse rotation
#pragma unroll
  for (int it = 0; it < 3; it++) {
    const int c = it * 256 + tid;
    if (c < SEGL * 32) {
      const int j = c >> 5, off = (c & 31) * 8;
      const int hl = off >> 6, d = off & (DH - 1);
      const int colr = hl * DH + ((d + j * 8) & (DH - 1));
      *reinterpret_cast<uint4*>(ctx + (row0 + (size_t)j * B_BATCH) * D_MODEL + colbase + off) =
          *reinterpret_cast<const uint4*>(&kls[j][colr]);
    }
  }
}

// ---------- final: pooled = mean_b h ; out = pooled @ fc_w + fc_b ----------
__global__ __launch_bounds__(256)
void pool_fc(const float* __restrict__ h, const float* __restrict__ fcw,
             const float* __restrict__ fcb, float* __restrict__ out) {
  const int t = blockIdx.x, tid = threadIdx.x;
  float ax = 0, ay = 0, az = 0, aw = 0;
#pragma unroll
  for (int b = 0; b < B_BATCH; b++) {
    float4 v = reinterpret_cast<const float4*>(h + ((size_t)t * B_BATCH + b) * D_MODEL)[tid];
    ax += v.x; ay += v.y; az += v.z; aw += v.w;
  }
  const int d0 = tid * 4;
  float pacc[5];
#pragma unroll
  for (int c = 0; c < 5; c++)
    pacc[c] = (ax * fcw[(d0 + 0) * 5 + c] + ay * fcw[(d0 + 1) * 5 + c] +
               az * fcw[(d0 + 2) * 5 + c] + aw * fcw[(d0 + 3) * 5 + c]) * (1.0f / B_BATCH);
#pragma unroll
  for (int off = 32; off >= 1; off >>= 1)
#pragma unroll
    for (int c = 0; c < 5; c++) pacc[c] += __shfl_xor(pacc[c], off);
  __shared__ float red[4][5];
  if ((tid & 63) == 0) {
#pragma unroll
    for (int c = 0; c < 5; c++) red[tid >> 6][c] = pacc[c];
  }
  __syncthreads();
  if (tid < 5)
    out[(size_t)t * 5 + tid] = red[0][tid] + red[1][tid] + red[2][tid] + red[3][tid] + fcb[tid];
}

// ---------- launch ----------
extern "C" void kernel_launch(void* const* d_in, const int* in_sizes, int n_in,
                              void* d_out, int out_size, void* d_ws, size_t ws_size,
                              hipStream_t stream) {
  const float* x    = (const float*)d_in[0];
  const float* lnp  = (const float*)d_in[2];
  const float* Wq   = (const float*)d_in[3];
  const float* bq   = (const float*)d_in[4];
  const float* Wkv  = (const float*)d_in[5];
  const float* bkv  = (const float*)d_in[6];
  const float* Wout = (const float*)d_in[7];
  const float* bout = (const float*)d_in[8];
  const float* W1   = (const float*)d_in[9];
  const float* b1   = (const float*)d_in[10];
  const float* W2   = (const float*)d_in[11];
  const float* b2   = (const float*)d_in[12];
  const float* fcw  = (const float*)d_in[13];
  const float* fcb  = (const float*)d_in[14];

  char* p = (char*)d_ws;
  size_t off = 0;
  auto take = [&](size_t bytes) -> char* { char* q = p + off; off += (bytes + 255) & ~(size_t)255; return q; };

  // Minimal-footprint activation set (~393 MB):
  //  h   : fp32 residual stream, updated in place
  //  hn  : bf16 LN output
  //  qb  : bf16 q; attention ctx written in place over qb
  //  kvb : bf16 [k|v]; FFN intermediate f1 reuses this buffer
  float* h            = (float*)take((size_t)M_ROWS * D_MODEL * 4);
  __hip_bfloat16* hn  = (__hip_bfloat16*)take((size_t)M_ROWS * D_MODEL * 2);
  __hip_bfloat16* qb  = (__hip_bfloat16*)take((size_t)M_ROWS * D_MODEL * 2);
  __hip_bfloat16* kvb = (__hip_bfloat16*)take((size_t)M_ROWS * 2 * D_MODEL * 2);
  __hip_bfloat16* f1  = kvb;   // alias: kv dead once ctx computed

  const size_t WU = (size_t)L_LAYERS * D_MODEL * D_MODEL * 2;  // one DxD bf16 tensor, all layers
  const bool full = ws_size >= off + 6 * WU + (size_t)(16 << 20);

  __hip_bfloat16 *WqT, *WkvT, *WoutT, *W1T, *W2T;
  if (full) {
    WqT   = (__hip_bfloat16*)take(WU);
    WkvT  = (__hip_bfloat16*)take(2 * WU);
    WoutT = (__hip_bfloat16*)take(WU);
    W1T   = (__hip_bfloat16*)take(WU);
    W2T   = (__hip_bfloat16*)take(WU);
    trans_w<<<dim3(32, 32, L_LAYERS), 256, 0, stream>>>(Wq,   WqT,   D_MODEL, D_MODEL);
    trans_w<<<dim3(64, 32, L_LAYERS), 256, 0, stream>>>(Wkv,  WkvT,  D_MODEL, 2 * D_MODEL);
    trans_w<<<dim3(32, 32, L_LAYERS), 256, 0, stream>>>(Wout, WoutT, D_MODEL, D_MODEL);
    trans_w<<<dim3(32, 32, L_LAYERS), 256, 0, stream>>>(W1,   W1T,   D_MODEL, D_MODEL);
    trans_w<<<dim3(32, 32, L_LAYERS), 256, 0, stream>>>(W2,   W2T,   D_MODEL, D_MODEL);
  } else {
    // per-layer staging (12 MB total)
    WqT   = (__hip_bfloat16*)take((size_t)D_MODEL * D_MODEL * 2);
    WkvT  = (__hip_bfloat16*)take((size_t)D_MODEL * 2 * D_MODEL * 2);
    WoutT = (__hip_bfloat16*)take((size_t)D_MODEL * D_MODEL * 2);
    W1T   = (__hip_bfloat16*)take((size_t)D_MODEL * D_MODEL * 2);
    W2T   = (__hip_bfloat16*)take((size_t)D_MODEL * D_MODEL * 2);
  }

  xpose<<<M_ROWS, 256, 0, stream>>>(x, h);

  for (int l = 0; l < L_LAYERS; l++) {
    const size_t lw = (size_t)l * D_MODEL * D_MODEL;
    const __hip_bfloat16* wq   = full ? WqT   + lw     : WqT;
    const __hip_bfloat16* wkv  = full ? WkvT  + 2 * lw : WkvT;
    const __hip_bfloat16* wout = full ? WoutT + lw     : WoutT;
    const __hip_bfloat16* w1   = full ? W1T   + lw     : W1T;
    const __hip_bfloat16* w2   = full ? W2T   + lw     : W2T;
    if (!full) {
      trans_w<<<dim3(32, 32, 1), 256, 0, stream>>>(Wq + lw,      WqT,   D_MODEL, D_MODEL);
      trans_w<<<dim3(64, 32, 1), 256, 0, stream>>>(Wkv + 2 * lw, WkvT,  D_MODEL, 2 * D_MODEL);
      trans_w<<<dim3(32, 32, 1), 256, 0, stream>>>(Wout + lw,    WoutT, D_MODEL, D_MODEL);
      trans_w<<<dim3(32, 32, 1), 256, 0, stream>>>(W1 + lw,      W1T,   D_MODEL, D_MODEL);
      trans_w<<<dim3(32, 32, 1), 256, 0, stream>>>(W2 + lw,      W2T,   D_MODEL, D_MODEL);
    }
    const float* g0 = lnp + ((size_t)l * 6 + 0) * D_MODEL;
    const float* g1 = lnp + ((size_t)l * 6 + 1) * D_MODEL;
    const float* g2 = lnp + ((size_t)l * 6 + 2) * D_MODEL;
    const float* g3 = lnp + ((size_t)l * 6 + 3) * D_MODEL;
    const float* g4 = lnp + ((size_t)l * 6 + 4) * D_MODEL;
    const float* g5 = lnp + ((size_t)l * 6 + 5) * D_MODEL;

    ln_k<1><<<M_ROWS, 256, 0, stream>>>(h, hn, g0, g1);
    gemm_bt<EPI_BF16>  <<<dim3(8, 250),  256, 0, stream>>>(hn, wq,  bq  + l * D_MODEL,     nullptr, qb,  D_MODEL,     D_MODEL);
    gemm_bt<EPI_BF16>  <<<dim3(16, 250), 256, 0, stream>>>(hn, wkv, bkv + l * 2 * D_MODEL, nullptr, kvb, 2 * D_MODEL, D_MODEL);
    attn_k<<<NSEG * B_BATCH * HGN, 256, 0, stream>>>(qb, kvb, qb);         // ctx in place over q
    gemm_bt<EPI_F32RES><<<dim3(8, 250),  256, 0, stream>>>(qb, wout, bout + l * D_MODEL, h, h, D_MODEL, D_MODEL);  // h += attn_out
    ln_k<1><<<M_ROWS, 256, 0, stream>>>(h, hn, g2, g3);
    gemm_bt<EPI_RELU>  <<<dim3(8, 250),  256, 0, stream>>>(hn, w1, b1 + l * D_MODEL, nullptr, f1, D_MODEL, D_MODEL);
    gemm_bt<EPI_F32RES><<<dim3(8, 250),  256, 0, stream>>>(f1, w2, b2 + l * D_MODEL, h, h, D_MODEL, D_MODEL);      // h += ffn
    ln_k<0><<<M_ROWS, 256, 0, stream>>>(h, h, g4, g5);                     // in-place post LN
  }

  pool_fc<<<T_TIME, 256, 0, stream>>>(h, fcw, fcb, (float*)d_out);
}

// Round 8
// 11001.147 us; speedup vs baseline: 1.9094x; 1.0519x over previous
//
#include <hip/hip_runtime.h>
#include <hip/hip_bf16.h>

typedef __attribute__((ext_vector_type(4))) float f32x4;
typedef __attribute__((ext_vector_type(8))) __bf16 bf16x8;
typedef __attribute__((ext_vector_type(8))) unsigned short ushort8;

#define L_LAYERS 12
#define D_MODEL  1024
#define B_BATCH  16
#define T_TIME   2000
#define M_ROWS   (T_TIME * B_BATCH)   // 32000
#define H_HEADS  16
#define DH       64
#define SEGL     20
#define NSEG     (T_TIME / SEGL)      // 100
#define HGN      4                    // heads per attention block

// ---------- helpers ----------
__device__ __forceinline__ void gload_lds16(const void* g, void* l) {
  __builtin_amdgcn_global_load_lds((const __attribute__((address_space(1))) void*)g,
                                   (__attribute__((address_space(3))) void*)l, 16, 0, 0);
}
__device__ __forceinline__ float bf2f(unsigned short u) {
  union { unsigned int i; float f; } x; x.i = ((unsigned)u) << 16; return x.f;
}
__device__ __forceinline__ unsigned short f2bf(float f) {
  union { __hip_bfloat16 h; unsigned short u; } x; x.h = __float2bfloat16(f); return x.u;
}

// ---------- x (B,T,D) -> h (T*B, D) fp32 ----------
__global__ __launch_bounds__(256)
void xpose(const float* __restrict__ x, float* __restrict__ h) {
  const int r = blockIdx.x;            // r = t*16 + b
  const int t = r >> 4, b = r & 15;
  reinterpret_cast<float4*>(h + (size_t)r * D_MODEL)[threadIdx.x] =
      reinterpret_cast<const float4*>(x + ((size_t)b * T_TIME + t) * D_MODEL)[threadIdx.x];
}

// ---------- weight transpose fp32 W[Kd][Nd] -> bf16 Wt[Nd][Kd], batched over z ----------
__global__ __launch_bounds__(256)
void trans_w(const float* __restrict__ W, __hip_bfloat16* __restrict__ Wt, int Kd, int Nd) {
  __shared__ float tbuf[32][33];
  const size_t base = (size_t)blockIdx.z * Kd * Nd;
  const int n0 = blockIdx.x * 32, k0 = blockIdx.y * 32;
  const int tx = threadIdx.x & 31, ty = threadIdx.x >> 5;
#pragma unroll
  for (int i = 0; i < 4; i++)
    tbuf[ty + i * 8][tx] = W[base + (size_t)(k0 + ty + i * 8) * Nd + n0 + tx];
  __syncthreads();
#pragma unroll
  for (int i = 0; i < 4; i++)
    Wt[base + (size_t)(n0 + ty + i * 8) * Kd + k0 + tx] = __float2bfloat16(tbuf[tx][ty + i * 8]);
}

// ---------- LayerNorm: fp32 in, bf16 or fp32 out (in-place safe: row read before write) ----------
template <int BF16OUT>
__global__ __launch_bounds__(256)
void ln_k(const float* __restrict__ in, void* __restrict__ out,
          const float* __restrict__ gamma, const float* __restrict__ beta) {
  const int r = blockIdx.x, t = threadIdx.x;
  const float4 v = reinterpret_cast<const float4*>(in + (size_t)r * D_MODEL)[t];
  float s  = v.x + v.y + v.z + v.w;
  float sq = v.x * v.x + v.y * v.y + v.z * v.z + v.w * v.w;
#pragma unroll
  for (int off = 32; off >= 1; off >>= 1) {
    s  += __shfl_xor(s, off);
    sq += __shfl_xor(sq, off);
  }
  __shared__ float ss[4], ssq[4];
  if ((t & 63) == 0) { ss[t >> 6] = s; ssq[t >> 6] = sq; }
  __syncthreads();
  s  = ss[0] + ss[1] + ss[2] + ss[3];
  sq = ssq[0] + ssq[1] + ssq[2] + ssq[3];
  const float mu   = s * (1.0f / D_MODEL);
  const float var  = sq * (1.0f / D_MODEL) - mu * mu;
  const float rstd = rsqrtf(var + 1e-5f);
  const float4 g = reinterpret_cast<const float4*>(gamma)[t];
  const float4 bb = reinterpret_cast<const float4*>(beta)[t];
  const float o0 = (v.x - mu) * rstd * g.x + bb.x;
  const float o1 = (v.y - mu) * rstd * g.y + bb.y;
  const float o2 = (v.z - mu) * rstd * g.z + bb.z;
  const float o3 = (v.w - mu) * rstd * g.w + bb.w;
  if constexpr (BF16OUT) {
    unsigned short pk[4] = {f2bf(o0), f2bf(o1), f2bf(o2), f2bf(o3)};
    *reinterpret_cast<uint2*>((__hip_bfloat16*)out + (size_t)r * D_MODEL + t * 4) =
        *reinterpret_cast<uint2*>(pk);
  } else {
    float4 o; o.x = o0; o.y = o1; o.z = o2; o.w = o3;
    reinterpret_cast<float4*>((float*)out)[(size_t)r * (D_MODEL / 4) + t] = o;
  }
}

// ---------- GEMM v2: 256x256 tile, BK=64, 8 waves, dbuf LDS + XOR swizzle ----------
// C(MxN) = A(MxK bf16) * Bt(NxK bf16)^T. M=32000 (125 tiles), N%256==0, K%64==0.
// LDS: linear global_load_lds dest + inverse-swizzled GLOBAL source + swizzled ds_read
// (chunk ^= row&7) -> conflict-free reads (rule #21). One barrier per 64-MFMA K-tile.
// Bijective XCD swizzle (m204), nt-fastest within each XCD's contiguous mt chunk.
enum { EPI_BF16 = 0, EPI_RELU = 1, EPI_F32RES = 2 };

template <int EPI>
__global__ __launch_bounds__(512, 2)
void gemm_bt(const __hip_bfloat16* __restrict__ A, const __hip_bfloat16* __restrict__ Bt,
             const float* __restrict__ bias, const float* __restrict__ resid,
             void* __restrict__ Cv, int N, int K) {
  __shared__ __hip_bfloat16 As[2][256][64];   // 64 KB
  __shared__ __hip_bfloat16 Bs[2][256][64];   // 64 KB
  const int tid = threadIdx.x;
  const int wv = tid >> 6, ln = tid & 63;
  const int NT = N >> 8;
  // bijective XCD swizzle: q8/r8 chunking over gridDim.x
  const int nwg = gridDim.x;
  const int q8 = nwg >> 3, r8 = nwg & 7;
  const int xcd = blockIdx.x & 7, lid = blockIdx.x >> 3;
  const int swz = (xcd < r8 ? xcd * (q8 + 1) : r8 * (q8 + 1) + (xcd - r8) * q8) + lid;
  const int mt = swz / NT, nt = swz % NT;

  const __hip_bfloat16* ag = A  + (size_t)mt * 256 * K;
  const __hip_bfloat16* bg = Bt + (size_t)nt * 256 * K;
  const int sr = tid >> 3, scc = tid & 7;     // staging row (per-it +64), chunk slot

  auto stage = [&](int buf, int k0) {
#pragma unroll
    for (int it = 0; it < 4; it++) {
      const int r = it * 64 + sr;
      const int cs = scc ^ (sr & 7);          // inverse swizzle on SOURCE
      gload_lds16(ag + (size_t)r * K + k0 + cs * 8,
                  (char*)&As[buf][0][0] + (it * 512 + tid) * 16);
    }
#pragma unroll
    for (int it = 0; it < 4; it++) {
      const int r = it * 64 + sr;
      const int cs = scc ^ (sr & 7);
      gload_lds16(bg + (size_t)r * K + k0 + cs * 8,
                  (char*)&Bs[buf][0][0] + (it * 512 + tid) * 16);
    }
  };

  const int wr = wv >> 2, wc = wv & 3;        // 2 x 4 wave grid, per-wave 128x64
  const int lr = ln & 15, lk = ln >> 4;
  const int l7 = lr & 7;
  f32x4 acc[8][4] = {};

  stage(0, 0);
  __syncthreads();
  int cur = 0;
  for (int k0 = 0; k0 < K; k0 += 64) {
    if (k0 + 64 < K) stage(cur ^ 1, k0 + 64); // prefetch next tile (in flight over MFMA)
    const char* ab = (const char*)&As[cur][0][0];
    const char* bb = (const char*)&Bs[cur][0][0];
#pragma unroll
    for (int kb = 0; kb < 2; kb++) {
      const int slot = (kb * 4 + lk) ^ l7;    // swizzled 16B chunk within row
      bf16x8 af[8], bfr[4];
#pragma unroll
      for (int m = 0; m < 8; m++)
        af[m] = *reinterpret_cast<const bf16x8*>(ab + ((wr * 128 + m * 16 + lr) * 8 + slot) * 16);
#pragma unroll
      for (int n = 0; n < 4; n++)
        bfr[n] = *reinterpret_cast<const bf16x8*>(bb + ((wc * 64 + n * 16 + lr) * 8 + slot) * 16);
#pragma unroll
      for (int m = 0; m < 8; m++)
#pragma unroll
        for (int n = 0; n < 4; n++)
          acc[m][n] = __builtin_amdgcn_mfma_f32_16x16x32_bf16(af[m], bfr[n], acc[m][n], 0, 0, 0);
      __builtin_amdgcn_sched_barrier(0);      // cap cross-kb load hoisting (VGPR)
    }
    __syncthreads();                          // drains prefetch vmcnt + lgkm; buffers swap-safe
    cur ^= 1;
  }
  // epilogue: C/D layout col=lane&15, row=(lane>>4)*4+j
#pragma unroll
  for (int n = 0; n < 4; n++) {
    const int col = nt * 256 + wc * 64 + n * 16 + lr;
    const float bv = bias[col];
#pragma unroll
    for (int m = 0; m < 8; m++) {
      const size_t rbase = (size_t)mt * 256 + wr * 128 + m * 16 + lk * 4;
#pragma unroll
      for (int j = 0; j < 4; j++) {
        const size_t idx = (rbase + j) * (size_t)N + col;
        float v = acc[m][n][j] + bv;
        if constexpr (EPI == EPI_RELU) v = fmaxf(v, 0.0f);
        if constexpr (EPI == EPI_F32RES) {
          ((float*)Cv)[idx] = v + resid[idx];
        } else {
          ((__hip_bfloat16*)Cv)[idx] = __float2bfloat16(v);
        }
      }
    }
  }
}

// ---------- block-diagonal attention (round-7 version, passing) ----------
__global__ __launch_bounds__(256, 4)
void attn_k(const __hip_bfloat16* __restrict__ q, const __hip_bfloat16* __restrict__ kv,
            __hip_bfloat16* __restrict__ ctx) {
  __shared__ __hip_bfloat16 kls[SEGL][HGN * DH];   // 10 KB: K slice; reused as ctx tile
  __shared__ __hip_bfloat16 vls[SEGL][HGN * DH];   // 10 KB: V slice
  __shared__ float sls[HGN][SEGL][SEGL];           // 6.4 KB: scores
  const int blk = blockIdx.x;
  const int hg = blk & 3;
  const int sb = blk >> 2;
  const int s = sb >> 4, b = sb & 15;
  const size_t row0 = (size_t)s * SEGL * B_BATCH + b;
  const int tid = threadIdx.x;
  const int colbase = hg * (HGN * DH);
#pragma unroll
  for (int it = 0; it < 3; it++) {
    const int c = it * 256 + tid;
    if (c < SEGL * 32) {
      const int j = c >> 5, off = (c & 31) * 8;
      gload_lds16(kv + (row0 + (size_t)j * B_BATCH) * (2 * D_MODEL) + colbase + off,
                  (char*)kls + c * 16);
    }
  }
#pragma unroll
  for (int it = 0; it < 3; it++) {
    const int c = it * 256 + tid;
    if (c < SEGL * 32) {
      const int j = c >> 5, off = (c & 31) * 8;
      gload_lds16(kv + (row0 + (size_t)j * B_BATCH) * (2 * D_MODEL) + D_MODEL + colbase + off,
                  (char*)vls + c * 16);
    }
  }
  const bool active = tid < HGN * SEGL;
  const int hh = tid / SEGL;
  const int i  = tid % SEGL;
  ushort8 qv[8];
  if (active) {
    const __hip_bfloat16* qp = q + (row0 + (size_t)i * B_BATCH) * D_MODEL + (colbase + hh * DH);
#pragma unroll
    for (int c = 0; c < 8; c++) qv[c] = reinterpret_cast<const ushort8*>(qp)[c];
  }
  __syncthreads();
  float inv = 0.0f;
  if (active) {
#pragma unroll 1
    for (int j = 0; j < SEGL; j++) {
      float a0 = 0, a1 = 0;
#pragma unroll
      for (int c = 0; c < 8; c++) {
        ushort8 u = *reinterpret_cast<const ushort8*>(&kls[j][hh * DH + c * 8]);
#pragma unroll
        for (int e = 0; e < 8; e += 2) {
          a0 += bf2f(qv[c][e]) * bf2f(u[e]);
          a1 += bf2f(qv[c][e + 1]) * bf2f(u[e + 1]);
        }
      }
      sls[hh][i][j] = (a0 + a1) * 0.125f;
    }
    float mx = -1e30f;
#pragma unroll 1
    for (int j = 0; j < SEGL; j++) mx = fmaxf(mx, sls[hh][i][j]);
    float sum = 0.0f;
#pragma unroll 1
    for (int j = 0; j < SEGL; j++) { float e = __expf(sls[hh][i][j] - mx); sls[hh][i][j] = e; sum += e; }
    inv = 1.0f / sum;
  }
  __syncthreads();
  if (active) {
#pragma unroll
    for (int d0 = 0; d0 < DH; d0 += 8) {
      float acc[8] = {};
#pragma unroll 1
      for (int j = 0; j < SEGL; j++) {
        const float pj = sls[hh][i][j];
        ushort8 u = *reinterpret_cast<const ushort8*>(&vls[j][hh * DH + d0]);
#pragma unroll
        for (int e = 0; e < 8; e++) acc[e] += pj * bf2f(u[e]);
      }
      unsigned short pk[8];
#pragma unroll
      for (int e = 0; e < 8; e++) pk[e] = f2bf(acc[e] * inv);
      const int colr = hh * DH + ((d0 + i * 8) & (DH - 1));
      *reinterpret_cast<uint4*>(&kls[i][colr]) = *reinterpret_cast<uint4*>(pk);
    }
  }
  __syncthreads();
#pragma unroll
  for (int it = 0; it < 3; it++) {
    const int c = it * 256 + tid;
    if (c < SEGL * 32) {
      const int j = c >> 5, off = (c & 31) * 8;
      const int hl = off >> 6, d = off & (DH - 1);
      const int colr = hl * DH + ((d + j * 8) & (DH - 1));
      *reinterpret_cast<uint4*>(ctx + (row0 + (size_t)j * B_BATCH) * D_MODEL + colbase + off) =
          *reinterpret_cast<const uint4*>(&kls[j][colr]);
    }
  }
}

// ---------- final: pooled = mean_b h ; out = pooled @ fc_w + fc_b ----------
__global__ __launch_bounds__(256)
void pool_fc(const float* __restrict__ h, const float* __restrict__ fcw,
             const float* __restrict__ fcb, float* __restrict__ out) {
  const int t = blockIdx.x, tid = threadIdx.x;
  float ax = 0, ay = 0, az = 0, aw = 0;
#pragma unroll
  for (int b = 0; b < B_BATCH; b++) {
    float4 v = reinterpret_cast<const float4*>(h + ((size_t)t * B_BATCH + b) * D_MODEL)[tid];
    ax += v.x; ay += v.y; az += v.z; aw += v.w;
  }
  const int d0 = tid * 4;
  float pacc[5];
#pragma unroll
  for (int c = 0; c < 5; c++)
    pacc[c] = (ax * fcw[(d0 + 0) * 5 + c] + ay * fcw[(d0 + 1) * 5 + c] +
               az * fcw[(d0 + 2) * 5 + c] + aw * fcw[(d0 + 3) * 5 + c]) * (1.0f / B_BATCH);
#pragma unroll
  for (int off = 32; off >= 1; off >>= 1)
#pragma unroll
    for (int c = 0; c < 5; c++) pacc[c] += __shfl_xor(pacc[c], off);
  __shared__ float red[4][5];
  if ((tid & 63) == 0) {
#pragma unroll
    for (int c = 0; c < 5; c++) red[tid >> 6][c] = pacc[c];
  }
  __syncthreads();
  if (tid < 5)
    out[(size_t)t * 5 + tid] = red[0][tid] + red[1][tid] + red[2][tid] + red[3][tid] + fcb[tid];
}

// ---------- launch ----------
extern "C" void kernel_launch(void* const* d_in, const int* in_sizes, int n_in,
                              void* d_out, int out_size, void* d_ws, size_t ws_size,
                              hipStream_t stream) {
  const float* x    = (const float*)d_in[0];
  const float* lnp  = (const float*)d_in[2];
  const float* Wq   = (const float*)d_in[3];
  const float* bq   = (const float*)d_in[4];
  const float* Wkv  = (const float*)d_in[5];
  const float* bkv  = (const float*)d_in[6];
  const float* Wout = (const float*)d_in[7];
  const float* bout = (const float*)d_in[8];
  const float* W1   = (const float*)d_in[9];
  const float* b1   = (const float*)d_in[10];
  const float* W2   = (const float*)d_in[11];
  const float* b2   = (const float*)d_in[12];
  const float* fcw  = (const float*)d_in[13];
  const float* fcb  = (const float*)d_in[14];

  char* p = (char*)d_ws;
  size_t off = 0;
  auto take = [&](size_t bytes) -> char* { char* q = p + off; off += (bytes + 255) & ~(size_t)255; return q; };

  float* h            = (float*)take((size_t)M_ROWS * D_MODEL * 4);
  __hip_bfloat16* hn  = (__hip_bfloat16*)take((size_t)M_ROWS * D_MODEL * 2);
  __hip_bfloat16* qb  = (__hip_bfloat16*)take((size_t)M_ROWS * D_MODEL * 2);
  __hip_bfloat16* kvb = (__hip_bfloat16*)take((size_t)M_ROWS * 2 * D_MODEL * 2);
  __hip_bfloat16* f1  = kvb;   // alias: kv dead once ctx computed

  const size_t WU = (size_t)L_LAYERS * D_MODEL * D_MODEL * 2;
  const bool full = ws_size >= off + 6 * WU + (size_t)(16 << 20);

  __hip_bfloat16 *WqT, *WkvT, *WoutT, *W1T, *W2T;
  if (full) {
    WqT   = (__hip_bfloat16*)take(WU);
    WkvT  = (__hip_bfloat16*)take(2 * WU);
    WoutT = (__hip_bfloat16*)take(WU);
    W1T   = (__hip_bfloat16*)take(WU);
    W2T   = (__hip_bfloat16*)take(WU);
    trans_w<<<dim3(32, 32, L_LAYERS), 256, 0, stream>>>(Wq,   WqT,   D_MODEL, D_MODEL);
    trans_w<<<dim3(64, 32, L_LAYERS), 256, 0, stream>>>(Wkv,  WkvT,  D_MODEL, 2 * D_MODEL);
    trans_w<<<dim3(32, 32, L_LAYERS), 256, 0, stream>>>(Wout, WoutT, D_MODEL, D_MODEL);
    trans_w<<<dim3(32, 32, L_LAYERS), 256, 0, stream>>>(W1,   W1T,   D_MODEL, D_MODEL);
    trans_w<<<dim3(32, 32, L_LAYERS), 256, 0, stream>>>(W2,   W2T,   D_MODEL, D_MODEL);
  } else {
    WqT   = (__hip_bfloat16*)take((size_t)D_MODEL * D_MODEL * 2);
    WkvT  = (__hip_bfloat16*)take((size_t)D_MODEL * 2 * D_MODEL * 2);
    WoutT = (__hip_bfloat16*)take((size_t)D_MODEL * D_MODEL * 2);
    W1T   = (__hip_bfloat16*)take((size_t)D_MODEL * D_MODEL * 2);
    W2T   = (__hip_bfloat16*)take((size_t)D_MODEL * D_MODEL * 2);
  }

  xpose<<<M_ROWS, 256, 0, stream>>>(x, h);

  for (int l = 0; l < L_LAYERS; l++) {
    const size_t lw = (size_t)l * D_MODEL * D_MODEL;
    const __hip_bfloat16* wq   = full ? WqT   + lw     : WqT;
    const __hip_bfloat16* wkv  = full ? WkvT  + 2 * lw : WkvT;
    const __hip_bfloat16* wout = full ? WoutT + lw     : WoutT;
    const __hip_bfloat16* w1   = full ? W1T   + lw     : W1T;
    const __hip_bfloat16* w2   = full ? W2T   + lw     : W2T;
    if (!full) {
      trans_w<<<dim3(32, 32, 1), 256, 0, stream>>>(Wq + lw,      WqT,   D_MODEL, D_MODEL);
      trans_w<<<dim3(64, 32, 1), 256, 0, stream>>>(Wkv + 2 * lw, WkvT,  D_MODEL, 2 * D_MODEL);
      trans_w<<<dim3(32, 32, 1), 256, 0, stream>>>(Wout + lw,    WoutT, D_MODEL, D_MODEL);
      trans_w<<<dim3(32, 32, 1), 256, 0, stream>>>(W1 + lw,      W1T,   D_MODEL, D_MODEL);
      trans_w<<<dim3(32, 32, 1), 256, 0, stream>>>(W2 + lw,      W2T,   D_MODEL, D_MODEL);
    }
    const float* g0 = lnp + ((size_t)l * 6 + 0) * D_MODEL;
    const float* g1 = lnp + ((size_t)l * 6 + 1) * D_MODEL;
    const float* g2 = lnp + ((size_t)l * 6 + 2) * D_MODEL;
    const float* g3 = lnp + ((size_t)l * 6 + 3) * D_MODEL;
    const float* g4 = lnp + ((size_t)l * 6 + 4) * D_MODEL;
    const float* g5 = lnp + ((size_t)l * 6 + 5) * D_MODEL;

    ln_k<1><<<M_ROWS, 256, 0, stream>>>(h, hn, g0, g1);
    gemm_bt<EPI_BF16>  <<<dim3(4 * 125), 512, 0, stream>>>(hn, wq,  bq  + l * D_MODEL,     nullptr, qb,  D_MODEL,     D_MODEL);
    gemm_bt<EPI_BF16>  <<<dim3(8 * 125), 512, 0, stream>>>(hn, wkv, bkv + l * 2 * D_MODEL, nullptr, kvb, 2 * D_MODEL, D_MODEL);
    attn_k<<<NSEG * B_BATCH * HGN, 256, 0, stream>>>(qb, kvb, qb);         // ctx in place over q
    gemm_bt<EPI_F32RES><<<dim3(4 * 125), 512, 0, stream>>>(qb, wout, bout + l * D_MODEL, h, h, D_MODEL, D_MODEL);
    ln_k<1><<<M_ROWS, 256, 0, stream>>>(h, hn, g2, g3);
    gemm_bt<EPI_RELU>  <<<dim3(4 * 125), 512, 0, stream>>>(hn, w1, b1 + l * D_MODEL, nullptr, f1, D_MODEL, D_MODEL);
    gemm_bt<EPI_F32RES><<<dim3(4 * 125), 512, 0, stream>>>(f1, w2, b2 + l * D_MODEL, h, h, D_MODEL, D_MODEL);
    ln_k<0><<<M_ROWS, 256, 0, stream>>>(h, h, g4, g5);
  }

  pool_fc<<<T_TIME, 256, 0, stream>>>(h, fcw, fcb, (float*)d_out);
}

// Round 9
// 10670.138 us; speedup vs baseline: 1.9686x; 1.0310x over previous
//
#include <hip/hip_runtime.h>
#include <hip/hip_bf16.h>

typedef __attribute__((ext_vector_type(4))) float f32x4;
typedef __attribute__((ext_vector_type(8))) __bf16 bf16x8;
typedef __attribute__((ext_vector_type(8))) unsigned short ushort8;

#define L_LAYERS 12
#define D_MODEL  1024
#define B_BATCH  16
#define T_TIME   2000
#define M_ROWS   (T_TIME * B_BATCH)   // 32000
#define H_HEADS  16
#define DH       64
#define SEGL     20
#define NSEG     (T_TIME / SEGL)      // 100
#define HGN      4                    // heads per attention block

// ---------- helpers ----------
__device__ __forceinline__ void gload_lds16(const void* g, void* l) {
  __builtin_amdgcn_global_load_lds((const __attribute__((address_space(1))) void*)g,
                                   (__attribute__((address_space(3))) void*)l, 16, 0, 0);
}
__device__ __forceinline__ float bf2f(unsigned short u) {
  union { unsigned int i; float f; } x; x.i = ((unsigned)u) << 16; return x.f;
}
__device__ __forceinline__ unsigned short f2bf(float f) {
  union { __hip_bfloat16 h; unsigned short u; } x; x.h = __float2bfloat16(f); return x.u;
}

// ---------- x (B,T,D) -> h (T*B, D) fp32 ----------
__global__ __launch_bounds__(256)
void xpose(const float* __restrict__ x, float* __restrict__ h) {
  const int r = blockIdx.x;            // r = t*16 + b
  const int t = r >> 4, b = r & 15;
  reinterpret_cast<float4*>(h + (size_t)r * D_MODEL)[threadIdx.x] =
      reinterpret_cast<const float4*>(x + ((size_t)b * T_TIME + t) * D_MODEL)[threadIdx.x];
}

// ---------- weight transpose fp32 W[Kd][Nd] -> bf16 Wt[Nd][Kd], batched over z ----------
__global__ __launch_bounds__(256)
void trans_w(const float* __restrict__ W, __hip_bfloat16* __restrict__ Wt, int Kd, int Nd) {
  __shared__ float tbuf[32][33];
  const size_t base = (size_t)blockIdx.z * Kd * Nd;
  const int n0 = blockIdx.x * 32, k0 = blockIdx.y * 32;
  const int tx = threadIdx.x & 31, ty = threadIdx.x >> 5;
#pragma unroll
  for (int i = 0; i < 4; i++)
    tbuf[ty + i * 8][tx] = W[base + (size_t)(k0 + ty + i * 8) * Nd + n0 + tx];
  __syncthreads();
#pragma unroll
  for (int i = 0; i < 4; i++)
    Wt[base + (size_t)(n0 + ty + i * 8) * Kd + k0 + tx] = __float2bfloat16(tbuf[tx][ty + i * 8]);
}

// ---------- LayerNorm: fp32 in, bf16 or fp32 out (in-place safe: row read before write) ----------
template <int BF16OUT>
__global__ __launch_bounds__(256)
void ln_k(const float* __restrict__ in, void* __restrict__ out,
          const float* __restrict__ gamma, const float* __restrict__ beta) {
  const int r = blockIdx.x, t = threadIdx.x;
  const float4 v = reinterpret_cast<const float4*>(in + (size_t)r * D_MODEL)[t];
  float s  = v.x + v.y + v.z + v.w;
  float sq = v.x * v.x + v.y * v.y + v.z * v.z + v.w * v.w;
#pragma unroll
  for (int off = 32; off >= 1; off >>= 1) {
    s  += __shfl_xor(s, off);
    sq += __shfl_xor(sq, off);
  }
  __shared__ float ss[4], ssq[4];
  if ((t & 63) == 0) { ss[t >> 6] = s; ssq[t >> 6] = sq; }
  __syncthreads();
  s  = ss[0] + ss[1] + ss[2] + ss[3];
  sq = ssq[0] + ssq[1] + ssq[2] + ssq[3];
  const float mu   = s * (1.0f / D_MODEL);
  const float var  = sq * (1.0f / D_MODEL) - mu * mu;
  const float rstd = rsqrtf(var + 1e-5f);
  const float4 g = reinterpret_cast<const float4*>(gamma)[t];
  const float4 bb = reinterpret_cast<const float4*>(beta)[t];
  const float o0 = (v.x - mu) * rstd * g.x + bb.x;
  const float o1 = (v.y - mu) * rstd * g.y + bb.y;
  const float o2 = (v.z - mu) * rstd * g.z + bb.z;
  const float o3 = (v.w - mu) * rstd * g.w + bb.w;
  if constexpr (BF16OUT) {
    unsigned short pk[4] = {f2bf(o0), f2bf(o1), f2bf(o2), f2bf(o3)};
    *reinterpret_cast<uint2*>((__hip_bfloat16*)out + (size_t)r * D_MODEL + t * 4) =
        *reinterpret_cast<uint2*>(pk);
  } else {
    float4 o; o.x = o0; o.y = o1; o.z = o2; o.w = o3;
    reinterpret_cast<float4*>((float*)out)[(size_t)r * (D_MODEL / 4) + t] = o;
  }
}

// ---------- GEMM v3: 256x256, BK=64, dbuf + swizzle; UNFENCED quadrant interleave ----------
// Round-9 change: removed sched_barrier fences and split MFMA into (kb, m-quadrant)
// phases with <=8 live b128 frags, letting the compiler pipeline ds_reads of phase
// p+1 under MFMAs of phase p (fine-grained lgkmcnt). One barrier per 64-MFMA K-tile;
// 16 prefetch loads in flight across the whole compute phase.
enum { EPI_BF16 = 0, EPI_RELU = 1, EPI_F32RES = 2 };

template <int EPI>
__global__ __launch_bounds__(512, 2)
void gemm_bt(const __hip_bfloat16* __restrict__ A, const __hip_bfloat16* __restrict__ Bt,
             const float* __restrict__ bias, const float* __restrict__ resid,
             void* __restrict__ Cv, int N, int K) {
  __shared__ __hip_bfloat16 As[2][256][64];   // 64 KB
  __shared__ __hip_bfloat16 Bs[2][256][64];   // 64 KB
  const int tid = threadIdx.x;
  const int wv = tid >> 6, ln = tid & 63;
  const int NT = N >> 8;
  // bijective XCD swizzle
  const int nwg = gridDim.x;
  const int q8 = nwg >> 3, r8 = nwg & 7;
  const int xcd = blockIdx.x & 7, lid = blockIdx.x >> 3;
  const int swz = (xcd < r8 ? xcd * (q8 + 1) : r8 * (q8 + 1) + (xcd - r8) * q8) + lid;
  const int mt = swz / NT, nt = swz % NT;

  const __hip_bfloat16* ag = A  + (size_t)mt * 256 * K;
  const __hip_bfloat16* bg = Bt + (size_t)nt * 256 * K;
  const int sr = tid >> 3, scc = tid & 7;     // staging row base, chunk slot

  auto stage = [&](int buf, int k0) {
#pragma unroll
    for (int it = 0; it < 4; it++) {
      const int r = it * 64 + sr;
      const int cs = scc ^ (sr & 7);          // inverse swizzle on SOURCE
      gload_lds16(ag + (size_t)r * K + k0 + cs * 8,
                  (char*)&As[buf][0][0] + (it * 512 + tid) * 16);
    }
#pragma unroll
    for (int it = 0; it < 4; it++) {
      const int r = it * 64 + sr;
      const int cs = scc ^ (sr & 7);
      gload_lds16(bg + (size_t)r * K + k0 + cs * 8,
                  (char*)&Bs[buf][0][0] + (it * 512 + tid) * 16);
    }
  };

  const int wr = wv >> 2, wc = wv & 3;        // 2 x 4 wave grid, per-wave 128x64
  const int lr = ln & 15, lk = ln >> 4;
  const int l7 = lr & 7;
  f32x4 acc[8][4] = {};

  stage(0, 0);
  __syncthreads();
  int cur = 0;
  for (int k0 = 0; k0 < K; k0 += 64) {
    if (k0 + 64 < K) stage(cur ^ 1, k0 + 64); // 16 loads in flight over the whole tile
    const char* ab = (const char*)&As[cur][0][0];
    const char* bb = (const char*)&Bs[cur][0][0];
#pragma unroll
    for (int kb = 0; kb < 2; kb++) {
      const int slot = (kb * 4 + lk) ^ l7;    // swizzled 16B chunk within row
      bf16x8 bfr[4];
#pragma unroll
      for (int n = 0; n < 4; n++)
        bfr[n] = *reinterpret_cast<const bf16x8*>(bb + ((wc * 64 + n * 16 + lr) * 8 + slot) * 16);
#pragma unroll
      for (int mq = 0; mq < 2; mq++) {
        bf16x8 af[4];
#pragma unroll
        for (int m = 0; m < 4; m++)
          af[m] = *reinterpret_cast<const bf16x8*>(ab + ((wr * 128 + (mq * 4 + m) * 16 + lr) * 8 + slot) * 16);
#pragma unroll
        for (int m = 0; m < 4; m++)
#pragma unroll
          for (int n = 0; n < 4; n++)
            acc[mq * 4 + m][n] = __builtin_amdgcn_mfma_f32_16x16x32_bf16(af[m], bfr[n], acc[mq * 4 + m][n], 0, 0, 0);
      }
    }
    __syncthreads();                          // single barrier per K-tile
    cur ^= 1;
  }
  // epilogue: C/D layout col=lane&15, row=(lane>>4)*4+j
#pragma unroll
  for (int n = 0; n < 4; n++) {
    const int col = nt * 256 + wc * 64 + n * 16 + lr;
    const float bv = bias[col];
#pragma unroll
    for (int m = 0; m < 8; m++) {
      const size_t rbase = (size_t)mt * 256 + wr * 128 + m * 16 + lk * 4;
#pragma unroll
      for (int j = 0; j < 4; j++) {
        const size_t idx = (rbase + j) * (size_t)N + col;
        float v = acc[m][n][j] + bv;
        if constexpr (EPI == EPI_RELU) v = fmaxf(v, 0.0f);
        if constexpr (EPI == EPI_F32RES) {
          ((float*)Cv)[idx] = v + resid[idx];
        } else {
          ((__hip_bfloat16*)Cv)[idx] = __float2bfloat16(v);
        }
      }
    }
  }
}

// ---------- block-diagonal attention (round-7 version, passing) ----------
__global__ __launch_bounds__(256, 4)
void attn_k(const __hip_bfloat16* __restrict__ q, const __hip_bfloat16* __restrict__ kv,
            __hip_bfloat16* __restrict__ ctx) {
  __shared__ __hip_bfloat16 kls[SEGL][HGN * DH];   // 10 KB: K slice; reused as ctx tile
  __shared__ __hip_bfloat16 vls[SEGL][HGN * DH];   // 10 KB: V slice
  __shared__ float sls[HGN][SEGL][SEGL];           // 6.4 KB: scores
  const int blk = blockIdx.x;
  const int hg = blk & 3;
  const int sb = blk >> 2;
  const int s = sb >> 4, b = sb & 15;
  const size_t row0 = (size_t)s * SEGL * B_BATCH + b;
  const int tid = threadIdx.x;
  const int colbase = hg * (HGN * DH);
#pragma unroll
  for (int it = 0; it < 3; it++) {
    const int c = it * 256 + tid;
    if (c < SEGL * 32) {
      const int j = c >> 5, off = (c & 31) * 8;
      gload_lds16(kv + (row0 + (size_t)j * B_BATCH) * (2 * D_MODEL) + colbase + off,
                  (char*)kls + c * 16);
    }
  }
#pragma unroll
  for (int it = 0; it < 3; it++) {
    const int c = it * 256 + tid;
    if (c < SEGL * 32) {
      const int j = c >> 5, off = (c & 31) * 8;
      gload_lds16(kv + (row0 + (size_t)j * B_BATCH) * (2 * D_MODEL) + D_MODEL + colbase + off,
                  (char*)vls + c * 16);
    }
  }
  const bool active = tid < HGN * SEGL;
  const int hh = tid / SEGL;
  const int i  = tid % SEGL;
  ushort8 qv[8];
  if (active) {
    const __hip_bfloat16* qp = q + (row0 + (size_t)i * B_BATCH) * D_MODEL + (colbase + hh * DH);
#pragma unroll
    for (int c = 0; c < 8; c++) qv[c] = reinterpret_cast<const ushort8*>(qp)[c];
  }
  __syncthreads();
  float inv = 0.0f;
  if (active) {
#pragma unroll 1
    for (int j = 0; j < SEGL; j++) {
      float a0 = 0, a1 = 0;
#pragma unroll
      for (int c = 0; c < 8; c++) {
        ushort8 u = *reinterpret_cast<const ushort8*>(&kls[j][hh * DH + c * 8]);
#pragma unroll
        for (int e = 0; e < 8; e += 2) {
          a0 += bf2f(qv[c][e]) * bf2f(u[e]);
          a1 += bf2f(qv[c][e + 1]) * bf2f(u[e + 1]);
        }
      }
      sls[hh][i][j] = (a0 + a1) * 0.125f;
    }
    float mx = -1e30f;
#pragma unroll 1
    for (int j = 0; j < SEGL; j++) mx = fmaxf(mx, sls[hh][i][j]);
    float sum = 0.0f;
#pragma unroll 1
    for (int j = 0; j < SEGL; j++) { float e = __expf(sls[hh][i][j] - mx); sls[hh][i][j] = e; sum += e; }
    inv = 1.0f / sum;
  }
  __syncthreads();
  if (active) {
#pragma unroll
    for (int d0 = 0; d0 < DH; d0 += 8) {
      float acc[8] = {};
#pragma unroll 1
      for (int j = 0; j < SEGL; j++) {
        const float pj = sls[hh][i][j];
        ushort8 u = *reinterpret_cast<const ushort8*>(&vls[j][hh * DH + d0]);
#pragma unroll
        for (int e = 0; e < 8; e++) acc[e] += pj * bf2f(u[e]);
      }
      unsigned short pk[8];
#pragma unroll
      for (int e = 0; e < 8; e++) pk[e] = f2bf(acc[e] * inv);
      const int colr = hh * DH + ((d0 + i * 8) & (DH - 1));
      *reinterpret_cast<uint4*>(&kls[i][colr]) = *reinterpret_cast<uint4*>(pk);
    }
  }
  __syncthreads();
#pragma unroll
  for (int it = 0; it < 3; it++) {
    const int c = it * 256 + tid;
    if (c < SEGL * 32) {
      const int j = c >> 5, off = (c & 31) * 8;
      const int hl = off >> 6, d = off & (DH - 1);
      const int colr = hl * DH + ((d + j * 8) & (DH - 1));
      *reinterpret_cast<uint4*>(ctx + (row0 + (size_t)j * B_BATCH) * D_MODEL + colbase + off) =
          *reinterpret_cast<const uint4*>(&kls[j][colr]);
    }
  }
}

// ---------- final: pooled = mean_b h ; out = pooled @ fc_w + fc_b ----------
__global__ __launch_bounds__(256)
void pool_fc(const float* __restrict__ h, const float* __restrict__ fcw,
             const float* __restrict__ fcb, float* __restrict__ out) {
  const int t = blockIdx.x, tid = threadIdx.x;
  float ax = 0, ay = 0, az = 0, aw = 0;
#pragma unroll
  for (int b = 0; b < B_BATCH; b++) {
    float4 v = reinterpret_cast<const float4*>(h + ((size_t)t * B_BATCH + b) * D_MODEL)[tid];
    ax += v.x; ay += v.y; az += v.z; aw += v.w;
  }
  const int d0 = tid * 4;
  float pacc[5];
#pragma unroll
  for (int c = 0; c < 5; c++)
    pacc[c] = (ax * fcw[(d0 + 0) * 5 + c] + ay * fcw[(d0 + 1) * 5 + c] +
               az * fcw[(d0 + 2) * 5 + c] + aw * fcw[(d0 + 3) * 5 + c]) * (1.0f / B_BATCH);
#pragma unroll
  for (int off = 32; off >= 1; off >>= 1)
#pragma unroll
    for (int c = 0; c < 5; c++) pacc[c] += __shfl_xor(pacc[c], off);
  __shared__ float red[4][5];
  if ((tid & 63) == 0) {
#pragma unroll
    for (int c = 0; c < 5; c++) red[tid >> 6][c] = pacc[c];
  }
  __syncthreads();
  if (tid < 5)
    out[(size_t)t * 5 + tid] = red[0][tid] + red[1][tid] + red[2][tid] + red[3][tid] + fcb[tid];
}

// ---------- launch ----------
extern "C" void kernel_launch(void* const* d_in, const int* in_sizes, int n_in,
                              void* d_out, int out_size, void* d_ws, size_t ws_size,
                              hipStream_t stream) {
  const float* x    = (const float*)d_in[0];
  const float* lnp  = (const float*)d_in[2];
  const float* Wq   = (const float*)d_in[3];
  const float* bq   = (const float*)d_in[4];
  const float* Wkv  = (const float*)d_in[5];
  const float* bkv  = (const float*)d_in[6];
  const float* Wout = (const float*)d_in[7];
  const float* bout = (const float*)d_in[8];
  const float* W1   = (const float*)d_in[9];
  const float* b1   = (const float*)d_in[10];
  const float* W2   = (const float*)d_in[11];
  const float* b2   = (const float*)d_in[12];
  const float* fcw  = (const float*)d_in[13];
  const float* fcb  = (const float*)d_in[14];

  char* p = (char*)d_ws;
  size_t off = 0;
  auto take = [&](size_t bytes) -> char* { char* q = p + off; off += (bytes + 255) & ~(size_t)255; return q; };

  float* h            = (float*)take((size_t)M_ROWS * D_MODEL * 4);
  __hip_bfloat16* hn  = (__hip_bfloat16*)take((size_t)M_ROWS * D_MODEL * 2);
  __hip_bfloat16* qb  = (__hip_bfloat16*)take((size_t)M_ROWS * D_MODEL * 2);
  __hip_bfloat16* kvb = (__hip_bfloat16*)take((size_t)M_ROWS * 2 * D_MODEL * 2);
  __hip_bfloat16* f1  = kvb;   // alias: kv dead once ctx computed

  const size_t WU = (size_t)L_LAYERS * D_MODEL * D_MODEL * 2;
  const bool full = ws_size >= off + 6 * WU + (size_t)(16 << 20);

  __hip_bfloat16 *WqT, *WkvT, *WoutT, *W1T, *W2T;
  if (full) {
    WqT   = (__hip_bfloat16*)take(WU);
    WkvT  = (__hip_bfloat16*)take(2 * WU);
    WoutT = (__hip_bfloat16*)take(WU);
    W1T   = (__hip_bfloat16*)take(WU);
    W2T   = (__hip_bfloat16*)take(WU);
    trans_w<<<dim3(32, 32, L_LAYERS), 256, 0, stream>>>(Wq,   WqT,   D_MODEL, D_MODEL);
    trans_w<<<dim3(64, 32, L_LAYERS), 256, 0, stream>>>(Wkv,  WkvT,  D_MODEL, 2 * D_MODEL);
    trans_w<<<dim3(32, 32, L_LAYERS), 256, 0, stream>>>(Wout, WoutT, D_MODEL, D_MODEL);
    trans_w<<<dim3(32, 32, L_LAYERS), 256, 0, stream>>>(W1,   W1T,   D_MODEL, D_MODEL);
    trans_w<<<dim3(32, 32, L_LAYERS), 256, 0, stream>>>(W2,   W2T,   D_MODEL, D_MODEL);
  } else {
    WqT   = (__hip_bfloat16*)take((size_t)D_MODEL * D_MODEL * 2);
    WkvT  = (__hip_bfloat16*)take((size_t)D_MODEL * 2 * D_MODEL * 2);
    WoutT = (__hip_bfloat16*)take((size_t)D_MODEL * D_MODEL * 2);
    W1T   = (__hip_bfloat16*)take((size_t)D_MODEL * D_MODEL * 2);
    W2T   = (__hip_bfloat16*)take((size_t)D_MODEL * D_MODEL * 2);
  }

  xpose<<<M_ROWS, 256, 0, stream>>>(x, h);

  for (int l = 0; l < L_LAYERS; l++) {
    const size_t lw = (size_t)l * D_MODEL * D_MODEL;
    const __hip_bfloat16* wq   = full ? WqT   + lw     : WqT;
    const __hip_bfloat16* wkv  = full ? WkvT  + 2 * lw : WkvT;
    const __hip_bfloat16* wout = full ? WoutT + lw     : WoutT;
    const __hip_bfloat16* w1   = full ? W1T   + lw     : W1T;
    const __hip_bfloat16* w2   = full ? W2T   + lw     : W2T;
    if (!full) {
      trans_w<<<dim3(32, 32, 1), 256, 0, stream>>>(Wq + lw,      WqT,   D_MODEL, D_MODEL);
      trans_w<<<dim3(64, 32, 1), 256, 0, stream>>>(Wkv + 2 * lw, WkvT,  D_MODEL, 2 * D_MODEL);
      trans_w<<<dim3(32, 32, 1), 256, 0, stream>>>(Wout + lw,    WoutT, D_MODEL, D_MODEL);
      trans_w<<<dim3(32, 32, 1), 256, 0, stream>>>(W1 + lw,      W1T,   D_MODEL, D_MODEL);
      trans_w<<<dim3(32, 32, 1), 256, 0, stream>>>(W2 + lw,      W2T,   D_MODEL, D_MODEL);
    }
    const float* g0 = lnp + ((size_t)l * 6 + 0) * D_MODEL;
    const float* g1 = lnp + ((size_t)l * 6 + 1) * D_MODEL;
    const float* g2 = lnp + ((size_t)l * 6 + 2) * D_MODEL;
    const float* g3 = lnp + ((size_t)l * 6 + 3) * D_MODEL;
    const float* g4 = lnp + ((size_t)l * 6 + 4) * D_MODEL;
    const float* g5 = lnp + ((size_t)l * 6 + 5) * D_MODEL;

    ln_k<1><<<M_ROWS, 256, 0, stream>>>(h, hn, g0, g1);
    gemm_bt<EPI_BF16>  <<<dim3(4 * 125), 512, 0, stream>>>(hn, wq,  bq  + l * D_MODEL,     nullptr, qb,  D_MODEL,     D_MODEL);
    gemm_bt<EPI_BF16>  <<<dim3(8 * 125), 512, 0, stream>>>(hn, wkv, bkv + l * 2 * D_MODEL, nullptr, kvb, 2 * D_MODEL, D_MODEL);
    attn_k<<<NSEG * B_BATCH * HGN, 256, 0, stream>>>(qb, kvb, qb);         // ctx in place over q
    gemm_bt<EPI_F32RES><<<dim3(4 * 125), 512, 0, stream>>>(qb, wout, bout + l * D_MODEL, h, h, D_MODEL, D_MODEL);
    ln_k<1><<<M_ROWS, 256, 0, stream>>>(h, hn, g2, g3);
    gemm_bt<EPI_RELU>  <<<dim3(4 * 125), 512, 0, stream>>>(hn, w1, b1 + l * D_MODEL, nullptr, f1, D_MODEL, D_MODEL);
    gemm_bt<EPI_F32RES><<<dim3(4 * 125), 512, 0, stream>>>(f1, w2, b2 + l * D_MODEL, h, h, D_MODEL, D_MODEL);
    ln_k<0><<<M_ROWS, 256, 0, stream>>>(h, h, g4, g5);
  }

  pool_fc<<<T_TIME, 256, 0, stream>>>(h, fcw, fcb, (float*)d_out);
}

// Round 10
// 10616.924 us; speedup vs baseline: 1.9785x; 1.0050x over previous
//
#include <hip/hip_runtime.h>
#include <hip/hip_bf16.h>

typedef __attribute__((ext_vector_type(4))) float f32x4;
typedef __attribute__((ext_vector_type(8))) __bf16 bf16x8;
typedef __attribute__((ext_vector_type(8))) unsigned short ushort8;

#define L_LAYERS 12
#define D_MODEL  1024
#define B_BATCH  16
#define T_TIME   2000
#define M_ROWS   (T_TIME * B_BATCH)   // 32000
#define H_HEADS  16
#define DH       64
#define SEGL     20
#define NSEG     (T_TIME / SEGL)      // 100
#define HGN      4                    // heads per attention block

// ---------- helpers ----------
__device__ __forceinline__ void gload_lds16(const void* g, void* l) {
  __builtin_amdgcn_global_load_lds((const __attribute__((address_space(1))) void*)g,
                                   (__attribute__((address_space(3))) void*)l, 16, 0, 0);
}
__device__ __forceinline__ float bf2f(unsigned short u) {
  union { unsigned int i; float f; } x; x.i = ((unsigned)u) << 16; return x.f;
}
__device__ __forceinline__ unsigned short f2bf(float f) {
  union { __hip_bfloat16 h; unsigned short u; } x; x.h = __float2bfloat16(f); return x.u;
}

// ---------- x (B,T,D) -> h (T*B, D) fp32 ----------
__global__ __launch_bounds__(256)
void xpose(const float* __restrict__ x, float* __restrict__ h) {
  const int r = blockIdx.x;            // r = t*16 + b
  const int t = r >> 4, b = r & 15;
  reinterpret_cast<float4*>(h + (size_t)r * D_MODEL)[threadIdx.x] =
      reinterpret_cast<const float4*>(x + ((size_t)b * T_TIME + t) * D_MODEL)[threadIdx.x];
}

// ---------- weight transpose fp32 W[Kd][Nd] -> bf16 Wt[Nd][Kd], batched over z ----------
__global__ __launch_bounds__(256)
void trans_w(const float* __restrict__ W, __hip_bfloat16* __restrict__ Wt, int Kd, int Nd) {
  __shared__ float tbuf[32][33];
  const size_t base = (size_t)blockIdx.z * Kd * Nd;
  const int n0 = blockIdx.x * 32, k0 = blockIdx.y * 32;
  const int tx = threadIdx.x & 31, ty = threadIdx.x >> 5;
#pragma unroll
  for (int i = 0; i < 4; i++)
    tbuf[ty + i * 8][tx] = W[base + (size_t)(k0 + ty + i * 8) * Nd + n0 + tx];
  __syncthreads();
#pragma unroll
  for (int i = 0; i < 4; i++)
    Wt[base + (size_t)(n0 + ty + i * 8) * Kd + k0 + tx] = __float2bfloat16(tbuf[tx][ty + i * 8]);
}

// ---------- LayerNorm: fp32 in, bf16 or fp32 out (in-place safe: row read before write) ----------
template <int BF16OUT>
__global__ __launch_bounds__(256)
void ln_k(const float* __restrict__ in, void* __restrict__ out,
          const float* __restrict__ gamma, const float* __restrict__ beta) {
  const int r = blockIdx.x, t = threadIdx.x;
  const float4 v = reinterpret_cast<const float4*>(in + (size_t)r * D_MODEL)[t];
  float s  = v.x + v.y + v.z + v.w;
  float sq = v.x * v.x + v.y * v.y + v.z * v.z + v.w * v.w;
#pragma unroll
  for (int off = 32; off >= 1; off >>= 1) {
    s  += __shfl_xor(s, off);
    sq += __shfl_xor(sq, off);
  }
  __shared__ float ss[4], ssq[4];
  if ((t & 63) == 0) { ss[t >> 6] = s; ssq[t >> 6] = sq; }
  __syncthreads();
  s  = ss[0] + ss[1] + ss[2] + ss[3];
  sq = ssq[0] + ssq[1] + ssq[2] + ssq[3];
  const float mu   = s * (1.0f / D_MODEL);
  const float var  = sq * (1.0f / D_MODEL) - mu * mu;
  const float rstd = rsqrtf(var + 1e-5f);
  const float4 g = reinterpret_cast<const float4*>(gamma)[t];
  const float4 bb = reinterpret_cast<const float4*>(beta)[t];
  const float o0 = (v.x - mu) * rstd * g.x + bb.x;
  const float o1 = (v.y - mu) * rstd * g.y + bb.y;
  const float o2 = (v.z - mu) * rstd * g.z + bb.z;
  const float o3 = (v.w - mu) * rstd * g.w + bb.w;
  if constexpr (BF16OUT) {
    unsigned short pk[4] = {f2bf(o0), f2bf(o1), f2bf(o2), f2bf(o3)};
    *reinterpret_cast<uint2*>((__hip_bfloat16*)out + (size_t)r * D_MODEL + t * 4) =
        *reinterpret_cast<uint2*>(pk);
  } else {
    float4 o; o.x = o0; o.y = o1; o.z = o2; o.w = o3;
    reinterpret_cast<float4*>((float*)out)[(size_t)r * (D_MODEL / 4) + t] = o;
  }
}

// ---------- GEMM v4: 256x256, BK=64, dbuf + swizzle; counted vmcnt, raw barriers ----------
// Round-10 change (T4): __syncthreads() full-drain replaced by raw s_barrier with
// counted s_waitcnt vmcnt(8) -- next tile's 8 prefetch loads stay in flight across
// both barriers and the whole compute phase; drain to 0 only at the last tile.
// Safety: buf written by stage(t+1) is read only after the next vmcnt+barrier pair;
// all reads of a buf are register-consumed (compiler lgkmcnt) before the end barrier,
// and its overwrite (stage t+2) is issued after that barrier. sched_barrier(0) fences
// ds_read motion across the LDS-overwrite boundaries.
enum { EPI_BF16 = 0, EPI_RELU = 1, EPI_F32RES = 2 };

template <int EPI>
__global__ __launch_bounds__(512, 2)
void gemm_bt(const __hip_bfloat16* __restrict__ A, const __hip_bfloat16* __restrict__ Bt,
             const float* __restrict__ bias, const float* __restrict__ resid,
             void* __restrict__ Cv, int N, int K) {
  __shared__ __hip_bfloat16 As[2][256][64];   // 64 KB
  __shared__ __hip_bfloat16 Bs[2][256][64];   // 64 KB
  const int tid = threadIdx.x;
  const int wv = tid >> 6, ln = tid & 63;
  const int NT = N >> 8;
  // bijective XCD swizzle
  const int nwg = gridDim.x;
  const int q8 = nwg >> 3, r8 = nwg & 7;
  const int xcd = blockIdx.x & 7, lid = blockIdx.x >> 3;
  const int swz = (xcd < r8 ? xcd * (q8 + 1) : r8 * (q8 + 1) + (xcd - r8) * q8) + lid;
  const int mt = swz / NT, nt = swz % NT;

  const __hip_bfloat16* ag = A  + (size_t)mt * 256 * K;
  const __hip_bfloat16* bg = Bt + (size_t)nt * 256 * K;
  const int sr = tid >> 3, scc = tid & 7;     // staging row base, chunk slot

  auto stage = [&](int buf, int k0) {         // 8 gload_lds per thread
#pragma unroll
    for (int it = 0; it < 4; it++) {
      const int r = it * 64 + sr;
      const int cs = scc ^ (sr & 7);          // inverse swizzle on SOURCE
      gload_lds16(ag + (size_t)r * K + k0 + cs * 8,
                  (char*)&As[buf][0][0] + (it * 512 + tid) * 16);
    }
#pragma unroll
    for (int it = 0; it < 4; it++) {
      const int r = it * 64 + sr;
      const int cs = scc ^ (sr & 7);
      gload_lds16(bg + (size_t)r * K + k0 + cs * 8,
                  (char*)&Bs[buf][0][0] + (it * 512 + tid) * 16);
    }
  };

  const int wr = wv >> 2, wc = wv & 3;        // 2 x 4 wave grid, per-wave 128x64
  const int lr = ln & 15, lk = ln >> 4;
  const int l7 = lr & 7;
  f32x4 acc[8][4] = {};

  stage(0, 0);
  int cur = 0;
  const int ntiles = K >> 6;
  for (int t = 0; t < ntiles; ++t) {
    const int k0 = t << 6;
    if (t + 1 < ntiles) {
      stage(cur ^ 1, k0 + 64);                // 8 loads for t+1: stay in flight
      asm volatile("s_waitcnt vmcnt(8)" ::: "memory");   // tile t's loads landed
    } else {
      asm volatile("s_waitcnt vmcnt(0)" ::: "memory");   // final tile: full drain
    }
    __builtin_amdgcn_s_barrier();             // all waves' tile-t loads visible
    __builtin_amdgcn_sched_barrier(0);
    const char* ab = (const char*)&As[cur][0][0];
    const char* bb = (const char*)&Bs[cur][0][0];
#pragma unroll
    for (int kb = 0; kb < 2; kb++) {
      const int slot = (kb * 4 + lk) ^ l7;    // swizzled 16B chunk within row
      bf16x8 bfr[4];
#pragma unroll
      for (int n = 0; n < 4; n++)
        bfr[n] = *reinterpret_cast<const bf16x8*>(bb + ((wc * 64 + n * 16 + lr) * 8 + slot) * 16);
#pragma unroll
      for (int mq = 0; mq < 2; mq++) {
        bf16x8 af[4];
#pragma unroll
        for (int m = 0; m < 4; m++)
          af[m] = *reinterpret_cast<const bf16x8*>(ab + ((wr * 128 + (mq * 4 + m) * 16 + lr) * 8 + slot) * 16);
#pragma unroll
        for (int m = 0; m < 4; m++)
#pragma unroll
          for (int n = 0; n < 4; n++)
            acc[mq * 4 + m][n] = __builtin_amdgcn_mfma_f32_16x16x32_bf16(af[m], bfr[n], acc[mq * 4 + m][n], 0, 0, 0);
      }
    }
    __builtin_amdgcn_sched_barrier(0);
    __builtin_amdgcn_s_barrier();             // all waves done reading buf[cur]
    cur ^= 1;
  }
  // epilogue: C/D layout col=lane&15, row=(lane>>4)*4+j
#pragma unroll
  for (int n = 0; n < 4; n++) {
    const int col = nt * 256 + wc * 64 + n * 16 + lr;
    const float bv = bias[col];
#pragma unroll
    for (int m = 0; m < 8; m++) {
      const size_t rbase = (size_t)mt * 256 + wr * 128 + m * 16 + lk * 4;
#pragma unroll
      for (int j = 0; j < 4; j++) {
        const size_t idx = (rbase + j) * (size_t)N + col;
        float v = acc[m][n][j] + bv;
        if constexpr (EPI == EPI_RELU) v = fmaxf(v, 0.0f);
        if constexpr (EPI == EPI_F32RES) {
          ((float*)Cv)[idx] = v + resid[idx];
        } else {
          ((__hip_bfloat16*)Cv)[idx] = __float2bfloat16(v);
        }
      }
    }
  }
}

// ---------- block-diagonal attention (round-7 version, passing) ----------
__global__ __launch_bounds__(256, 4)
void attn_k(const __hip_bfloat16* __restrict__ q, const __hip_bfloat16* __restrict__ kv,
            __hip_bfloat16* __restrict__ ctx) {
  __shared__ __hip_bfloat16 kls[SEGL][HGN * DH];   // 10 KB: K slice; reused as ctx tile
  __shared__ __hip_bfloat16 vls[SEGL][HGN * DH];   // 10 KB: V slice
  __shared__ float sls[HGN][SEGL][SEGL];           // 6.4 KB: scores
  const int blk = blockIdx.x;
  const int hg = blk & 3;
  const int sb = blk >> 2;
  const int s = sb >> 4, b = sb & 15;
  const size_t row0 = (size_t)s * SEGL * B_BATCH + b;
  const int tid = threadIdx.x;
  const int colbase = hg * (HGN * DH);
#pragma unroll
  for (int it = 0; it < 3; it++) {
    const int c = it * 256 + tid;
    if (c < SEGL * 32) {
      const int j = c >> 5, off = (c & 31) * 8;
      gload_lds16(kv + (row0 + (size_t)j * B_BATCH) * (2 * D_MODEL) + colbase + off,
                  (char*)kls + c * 16);
    }
  }
#pragma unroll
  for (int it = 0; it < 3; it++) {
    const int c = it * 256 + tid;
    if (c < SEGL * 32) {
      const int j = c >> 5, off = (c & 31) * 8;
      gload_lds16(kv + (row0 + (size_t)j * B_BATCH) * (2 * D_MODEL) + D_MODEL + colbase + off,
                  (char*)vls + c * 16);
    }
  }
  const bool active = tid < HGN * SEGL;
  const int hh = tid / SEGL;
  const int i  = tid % SEGL;
  ushort8 qv[8];
  if (active) {
    const __hip_bfloat16* qp = q + (row0 + (size_t)i * B_BATCH) * D_MODEL + (colbase + hh * DH);
#pragma unroll
    for (int c = 0; c < 8; c++) qv[c] = reinterpret_cast<const ushort8*>(qp)[c];
  }
  __syncthreads();
  float inv = 0.0f;
  if (active) {
#pragma unroll 1
    for (int j = 0; j < SEGL; j++) {
      float a0 = 0, a1 = 0;
#pragma unroll
      for (int c = 0; c < 8; c++) {
        ushort8 u = *reinterpret_cast<const ushort8*>(&kls[j][hh * DH + c * 8]);
#pragma unroll
        for (int e = 0; e < 8; e += 2) {
          a0 += bf2f(qv[c][e]) * bf2f(u[e]);
          a1 += bf2f(qv[c][e + 1]) * bf2f(u[e + 1]);
        }
      }
      sls[hh][i][j] = (a0 + a1) * 0.125f;
    }
    float mx = -1e30f;
#pragma unroll 1
    for (int j = 0; j < SEGL; j++) mx = fmaxf(mx, sls[hh][i][j]);
    float sum = 0.0f;
#pragma unroll 1
    for (int j = 0; j < SEGL; j++) { float e = __expf(sls[hh][i][j] - mx); sls[hh][i][j] = e; sum += e; }
    inv = 1.0f / sum;
  }
  __syncthreads();
  if (active) {
#pragma unroll
    for (int d0 = 0; d0 < DH; d0 += 8) {
      float acc[8] = {};
#pragma unroll 1
      for (int j = 0; j < SEGL; j++) {
        const float pj = sls[hh][i][j];
        ushort8 u = *reinterpret_cast<const ushort8*>(&vls[j][hh * DH + d0]);
#pragma unroll
        for (int e = 0; e < 8; e++) acc[e] += pj * bf2f(u[e]);
      }
      unsigned short pk[8];
#pragma unroll
      for (int e = 0; e < 8; e++) pk[e] = f2bf(acc[e] * inv);
      const int colr = hh * DH + ((d0 + i * 8) & (DH - 1));
      *reinterpret_cast<uint4*>(&kls[i][colr]) = *reinterpret_cast<uint4*>(pk);
    }
  }
  __syncthreads();
#pragma unroll
  for (int it = 0; it < 3; it++) {
    const int c = it * 256 + tid;
    if (c < SEGL * 32) {
      const int j = c >> 5, off = (c & 31) * 8;
      const int hl = off >> 6, d = off & (DH - 1);
      const int colr = hl * DH + ((d + j * 8) & (DH - 1));
      *reinterpret_cast<uint4*>(ctx + (row0 + (size_t)j * B_BATCH) * D_MODEL + colbase + off) =
          *reinterpret_cast<const uint4*>(&kls[j][colr]);
    }
  }
}

// ---------- final: pooled = mean_b h ; out = pooled @ fc_w + fc_b ----------
__global__ __launch_bounds__(256)
void pool_fc(const float* __restrict__ h, const float* __restrict__ fcw,
             const float* __restrict__ fcb, float* __restrict__ out) {
  const int t = blockIdx.x, tid = threadIdx.x;
  float ax = 0, ay = 0, az = 0, aw = 0;
#pragma unroll
  for (int b = 0; b < B_BATCH; b++) {
    float4 v = reinterpret_cast<const float4*>(h + ((size_t)t * B_BATCH + b) * D_MODEL)[tid];
    ax += v.x; ay += v.y; az += v.z; aw += v.w;
  }
  const int d0 = tid * 4;
  float pacc[5];
#pragma unroll
  for (int c = 0; c < 5; c++)
    pacc[c] = (ax * fcw[(d0 + 0) * 5 + c] + ay * fcw[(d0 + 1) * 5 + c] +
               az * fcw[(d0 + 2) * 5 + c] + aw * fcw[(d0 + 3) * 5 + c]) * (1.0f / B_BATCH);
#pragma unroll
  for (int off = 32; off >= 1; off >>= 1)
#pragma unroll
    for (int c = 0; c < 5; c++) pacc[c] += __shfl_xor(pacc[c], off);
  __shared__ float red[4][5];
  if ((tid & 63) == 0) {
#pragma unroll
    for (int c = 0; c < 5; c++) red[tid >> 6][c] = pacc[c];
  }
  __syncthreads();
  if (tid < 5)
    out[(size_t)t * 5 + tid] = red[0][tid] + red[1][tid] + red[2][tid] + red[3][tid] + fcb[tid];
}

// ---------- launch ----------
extern "C" void kernel_launch(void* const* d_in, const int* in_sizes, int n_in,
                              void* d_out, int out_size, void* d_ws, size_t ws_size,
                              hipStream_t stream) {
  const float* x    = (const float*)d_in[0];
  const float* lnp  = (const float*)d_in[2];
  const float* Wq   = (const float*)d_in[3];
  const float* bq   = (const float*)d_in[4];
  const float* Wkv  = (const float*)d_in[5];
  const float* bkv  = (const float*)d_in[6];
  const float* Wout = (const float*)d_in[7];
  const float* bout = (const float*)d_in[8];
  const float* W1   = (const float*)d_in[9];
  const float* b1   = (const float*)d_in[10];
  const float* W2   = (const float*)d_in[11];
  const float* b2   = (const float*)d_in[12];
  const float* fcw  = (const float*)d_in[13];
  const float* fcb  = (const float*)d_in[14];

  char* p = (char*)d_ws;
  size_t off = 0;
  auto take = [&](size_t bytes) -> char* { char* q = p + off; off += (bytes + 255) & ~(size_t)255; return q; };

  float* h            = (float*)take((size_t)M_ROWS * D_MODEL * 4);
  __hip_bfloat16* hn  = (__hip_bfloat16*)take((size_t)M_ROWS * D_MODEL * 2);
  __hip_bfloat16* qb  = (__hip_bfloat16*)take((size_t)M_ROWS * D_MODEL * 2);
  __hip_bfloat16* kvb = (__hip_bfloat16*)take((size_t)M_ROWS * 2 * D_MODEL * 2);
  __hip_bfloat16* f1  = kvb;   // alias: kv dead once ctx computed

  const size_t WU = (size_t)L_LAYERS * D_MODEL * D_MODEL * 2;
  const bool full = ws_size >= off + 6 * WU + (size_t)(16 << 20);

  __hip_bfloat16 *WqT, *WkvT, *WoutT, *W1T, *W2T;
  if (full) {
    WqT   = (__hip_bfloat16*)take(WU);
    WkvT  = (__hip_bfloat16*)take(2 * WU);
    WoutT = (__hip_bfloat16*)take(WU);
    W1T   = (__hip_bfloat16*)take(WU);
    W2T   = (__hip_bfloat16*)take(WU);
    trans_w<<<dim3(32, 32, L_LAYERS), 256, 0, stream>>>(Wq,   WqT,   D_MODEL, D_MODEL);
    trans_w<<<dim3(64, 32, L_LAYERS), 256, 0, stream>>>(Wkv,  WkvT,  D_MODEL, 2 * D_MODEL);
    trans_w<<<dim3(32, 32, L_LAYERS), 256, 0, stream>>>(Wout, WoutT, D_MODEL, D_MODEL);
    trans_w<<<dim3(32, 32, L_LAYERS), 256, 0, stream>>>(W1,   W1T,   D_MODEL, D_MODEL);
    trans_w<<<dim3(32, 32, L_LAYERS), 256, 0, stream>>>(W2,   W2T,   D_MODEL, D_MODEL);
  } else {
    WqT   = (__hip_bfloat16*)take((size_t)D_MODEL * D_MODEL * 2);
    WkvT  = (__hip_bfloat16*)take((size_t)D_MODEL * 2 * D_MODEL * 2);
    WoutT = (__hip_bfloat16*)take((size_t)D_MODEL * D_MODEL * 2);
    W1T   = (__hip_bfloat16*)take((size_t)D_MODEL * D_MODEL * 2);
    W2T   = (__hip_bfloat16*)take((size_t)D_MODEL * D_MODEL * 2);
  }

  xpose<<<M_ROWS, 256, 0, stream>>>(x, h);

  for (int l = 0; l < L_LAYERS; l++) {
    const size_t lw = (size_t)l * D_MODEL * D_MODEL;
    const __hip_bfloat16* wq   = full ? WqT   + lw     : WqT;
    const __hip_bfloat16* wkv  = full ? WkvT  + 2 * lw : WkvT;
    const __hip_bfloat16* wout = full ? WoutT + lw     : WoutT;
    const __hip_bfloat16* w1   = full ? W1T   + lw     : W1T;
    const __hip_bfloat16* w2   = full ? W2T   + lw     : W2T;
    if (!full) {
      trans_w<<<dim3(32, 32, 1), 256, 0, stream>>>(Wq + lw,      WqT,   D_MODEL, D_MODEL);
      trans_w<<<dim3(64, 32, 1), 256, 0, stream>>>(Wkv + 2 * lw, WkvT,  D_MODEL, 2 * D_MODEL);
      trans_w<<<dim3(32, 32, 1), 256, 0, stream>>>(Wout + lw,    WoutT, D_MODEL, D_MODEL);
      trans_w<<<dim3(32, 32, 1), 256, 0, stream>>>(W1 + lw,      W1T,   D_MODEL, D_MODEL);
      trans_w<<<dim3(32, 32, 1), 256, 0, stream>>>(W2 + lw,      W2T,   D_MODEL, D_MODEL);
    }
    const float* g0 = lnp + ((size_t)l * 6 + 0) * D_MODEL;
    const float* g1 = lnp + ((size_t)l * 6 + 1) * D_MODEL;
    const float* g2 = lnp + ((size_t)l * 6 + 2) * D_MODEL;
    const float* g3 = lnp + ((size_t)l * 6 + 3) * D_MODEL;
    const float* g4 = lnp + ((size_t)l * 6 + 4) * D_MODEL;
    const float* g5 = lnp + ((size_t)l * 6 + 5) * D_MODEL;

    ln_k<1><<<M_ROWS, 256, 0, stream>>>(h, hn, g0, g1);
    gemm_bt<EPI_BF16>  <<<dim3(4 * 125), 512, 0, stream>>>(hn, wq,  bq  + l * D_MODEL,     nullptr, qb,  D_MODEL,     D_MODEL);
    gemm_bt<EPI_BF16>  <<<dim3(8 * 125), 512, 0, stream>>>(hn, wkv, bkv + l * 2 * D_MODEL, nullptr, kvb, 2 * D_MODEL, D_MODEL);
    attn_k<<<NSEG * B_BATCH * HGN, 256, 0, stream>>>(qb, kvb, qb);         // ctx in place over q
    gemm_bt<EPI_F32RES><<<dim3(4 * 125), 512, 0, stream>>>(qb, wout, bout + l * D_MODEL, h, h, D_MODEL, D_MODEL);
    ln_k<1><<<M_ROWS, 256, 0, stream>>>(h, hn, g2, g3);
    gemm_bt<EPI_RELU>  <<<dim3(4 * 125), 512, 0, stream>>>(hn, w1, b1 + l * D_MODEL, nullptr, f1, D_MODEL, D_MODEL);
    gemm_bt<EPI_F32RES><<<dim3(4 * 125), 512, 0, stream>>>(f1, w2, b2 + l * D_MODEL, h, h, D_MODEL, D_MODEL);
    ln_k<0><<<M_ROWS, 256, 0, stream>>>(h, h, g4, g5);
  }

  pool_fc<<<T_TIME, 256, 0, stream>>>(h, fcw, fcb, (float*)d_out);
}